// Round 13
// baseline (477.330 us; speedup 1.0000x reference)
//
#include <hip/hip_runtime.h>
#include <stdint.h>

typedef __attribute__((ext_vector_type(8))) short short8;
typedef __attribute__((ext_vector_type(4))) float f32x4;

#define MFMA16(a,b,c) __builtin_amdgcn_mfma_f32_16x16x32_bf16((a),(b),(c),0,0,0)

// async global->LDS DMA, 16B per lane; LDS dest = wave-uniform base + lane*16B
#define GLL16(g, l) __builtin_amdgcn_global_load_lds( \
    (const __attribute__((address_space(1))) void*)(g), \
    (__attribute__((address_space(3))) void*)(l), 16, 0, 0)

__device__ __forceinline__ unsigned short f2bf(float f){
  unsigned u = __builtin_bit_cast(unsigned, f);
  u += 0x7fffu + ((u >> 16) & 1u);
  return (unsigned short)(u >> 16);
}
__device__ __forceinline__ float bf2f(unsigned short s){
  unsigned u = ((unsigned)s) << 16;
  return __builtin_bit_cast(float, u);
}
// cheap packed f32->2xbf16 (round-to-nearest, ties-away): a -> low16, b -> high16
__device__ __forceinline__ unsigned pk2(float a, float b){
  unsigned ua = __builtin_bit_cast(unsigned, a) + 0x8000u;
  unsigned ub = __builtin_bit_cast(unsigned, b) + 0x8000u;
  return (ub & 0xffff0000u) | (ua >> 16);
}
__device__ __forceinline__ unsigned long long pack4(f32x4 v){
  return (unsigned long long)pk2(v[0], v[1]) | ((unsigned long long)pk2(v[2], v[3]) << 32);
}

static constexpr int HW_ = 50176;   // 224*224

// offset of element (row r 0..127, k c64 0..63) inside one 8192-elem panel,
// XOR-swizzled so ds_read_b128 of a 16-lane column slice is conflict-free
__device__ __forceinline__ int panel_off(int r, int c64){
  return r * 64 + ((((c64 >> 3) ^ (r & 7))) << 3) + (c64 & 7);
}

// ---------------- weights fp32 -> bf16 ----------------
__global__ __launch_bounds__(256) void k_convw(const float* __restrict__ Wq, const float* __restrict__ Wk,
                        const float* __restrict__ Wv, const float* __restrict__ Wo,
                        unsigned short* __restrict__ Wf, unsigned short* __restrict__ Wob){
  int gid = blockIdx.x * 256 + threadIdx.x;   // grid 128 -> 32768
  if (gid < 24576){
    int lane = gid & 63;
    int r1 = gid >> 6;          // 0..383
    int t = r1 % 6;
    int r2 = r1 / 6;            // 0..63
    int kq = r2 & 7, hh = r2 >> 3;
    const float* W = (t < 2) ? Wq : (t < 4) ? Wk : Wv;
    int ch = hh * 32 + (t & 1) * 16 + (lane & 15);
    int k0 = kq * 32 + (lane >> 4) * 8;
    const float* src = W + ch * 256 + k0;
    float4 a = *(const float4*)src, b2 = *(const float4*)(src + 4);
    short8 v;
    v[0]=f2bf(a.x); v[1]=f2bf(a.y); v[2]=f2bf(a.z); v[3]=f2bf(a.w);
    v[4]=f2bf(b2.x); v[5]=f2bf(b2.y); v[6]=f2bf(b2.z); v[7]=f2bf(b2.w);
    *(short8*)(Wf + (size_t)gid * 8) = v;
  } else {
    int og = gid - 24576;       // 0..8191
    int o = og >> 5, ck = og & 31;
    const float* src = Wo + o * 256 + ck * 8;
    float4 a = *(const float4*)src, b2 = *(const float4*)(src + 4);
    short8 v;
    v[0]=f2bf(a.x); v[1]=f2bf(a.y); v[2]=f2bf(a.z); v[3]=f2bf(a.w);
    v[4]=f2bf(b2.x); v[5]=f2bf(b2.y); v[6]=f2bf(b2.z); v[7]=f2bf(b2.w);
    int kq = ck >> 3;
    int off = panel_off(o & 127, (ck & 7) * 8);
    *(short8*)(Wob + ((o >> 7) * 4 + kq) * 8192 + off) = v;
  }
}

// ---------------- x (B,C,H,W) f32 -> xw[win][half 2][px 49/64][128c swz] bf16 ----------------
__global__ __launch_bounds__(256) void k_xw(const float* __restrict__ x, unsigned short* __restrict__ xw){
  int bid = blockIdx.x;
  int cq = bid & 15, wh = (bid >> 4) & 31, b = bid >> 9;
  __shared__ __align__(16) unsigned short tile[25088];  // 49 KB
  int tid = threadIdx.x;
  for (int it = 0; it < 25; ++it){
    int idx = it * 256 + tid;
    if (idx < 6272){
      int c = idx & 15;
      int t2 = idx >> 4;                  // 0..391
      int r = t2 / 56;
      int w4 = t2 % 56;
      float4 v = *(const float4*)(x + ((size_t)(b * 256 + cq * 16 + c)) * HW_ + (wh * 7 + r) * 224 + w4 * 4);
      float vv[4] = {v.x, v.y, v.z, v.w};
      int w0 = w4 * 4;
      int ww = w0 / 7;
      int cl = w0 % 7;
#pragma unroll
      for (int i = 0; i < 4; ++i){
        int px = r * 7 + cl;
        tile[ww * 784 + px * 16 + (((c >> 3) ^ (px & 1)) << 3) + (c & 7)] = f2bf(vv[i]);
        if (++cl == 7){ cl = 0; ++ww; }
      }
    }
  }
  __syncthreads();
  size_t wb = ((size_t)(b * 1024 + wh * 32)) * 16384;
  for (int it = 0; it < 13; ++it){
    int id = it * 256 + tid;
    if (id < 3136){                       // 32 ww x 49 px x 2 chunk-slots
      int ww = id / 98;
      int rem = id - ww * 98;
      int px = rem >> 1, hb = rem & 1;
      short8 v = *(const short8*)(tile + ww * 784 + px * 16 + ((hb ^ (px & 1)) << 3));
      int cc = cq * 2 + hb;               // global 8-ch chunk 0..31
      int half = cc >> 4, c4 = cc & 15;
      int pos = (c4 & 8) | ((c4 ^ px) & 7);
      *(short8*)(xw + wb + (size_t)ww * 16384 + half * 8192 + px * 128 + pos * 8) = v;
    }
  }
}

// ---------------- fused: qkv GEMM + window attention ----------------
// block = (window, 4-head half), 4 waves = 4 heads, 48 KB LDS -> 3 blocks/CU
// x0 at [0,8192), x1 at [8192,16384) (overlapped DMA, counted vmcnt);
// q overwrites x1, vT overwrites x0 after a single post-phase-1 barrier.
__global__ __launch_bounds__(256, 3) void k_fused(const unsigned short* __restrict__ xw,
                                                  const unsigned short* __restrict__ Wf,
                                                  unsigned short* __restrict__ attnP){
  int bid = blockIdx.x;
  int wg = (bid & 7) * 1024 + (bid >> 3);   // 8192 = 8*1024; window pair on same XCD
  int hh = wg & 1; int win = wg >> 1;
  int b = win >> 10;
  int wh = (win >> 5) & 31, ww = win & 31;
  int tid = threadIdx.x;
  int lane = tid & 63;
  int hl = tid >> 6;                         // local head 0..3
  int hg = hh * 4 + hl;                      // global head

  __shared__ __align__(16) unsigned short lds[24576];   // 48 KB

  const unsigned short* xwin = xw + (size_t)win * 16384;

  // ---- phase 0: zero pad rows 49..63 of BOTH x buffers + overlapped DMA ----
  if (tid < 240){
    int rr = 49 + (tid >> 4), ck = tid & 15;
    short8 z = {};
    *(short8*)(lds + rr * 128 + ck * 8) = z;
    *(short8*)(lds + 8192 + rr * 128 + ck * 8) = z;
  }
#pragma unroll
  for (int it = 0; it < 4; ++it){
    int chunk = it * 256 + tid;              // x half0 -> [0,8192)
    if (chunk < 784) GLL16(xwin + chunk * 8, lds + chunk * 8);
  }
#pragma unroll
  for (int it = 0; it < 4; ++it){
    int chunk = it * 256 + tid;              // x half1 -> [8192,16384), stays in flight
    if (chunk < 784) GLL16(xwin + 8192 + chunk * 8, lds + 8192 + chunk * 8);
  }
  if (hl == 0) asm volatile("s_waitcnt vmcnt(4) lgkmcnt(0)" ::: "memory");  // wave0: 4 x1 ops remain
  else         asm volatile("s_waitcnt vmcnt(3) lgkmcnt(0)" ::: "memory");  // waves1-3: 3 remain
  __builtin_amdgcn_s_barrier();              // x0 (and zero-fill) visible to all waves

  // ---- phase 1: qkv GEMM; q,k transposed (D[ch][px]); v natural (D[px][ch]) ----
  f32x4 aqT[2][4] = {}, akT[2][4] = {}, avN[4][2] = {};
  for (int half = 0; half < 2; ++half){
    const unsigned short* xb = lds + half * 8192;
    for (int kq = 0; kq < 4; ++kq){
      short8 xf[4];
#pragma unroll
      for (int pt = 0; pt < 4; ++pt){
        int px = pt * 16 + (lane & 15);
        int c = kq * 4 + (lane >> 4);        // chunk 0..15
        int cs = (c & 8) | ((c ^ px) & 7);
        xf[pt] = *(const short8*)(xb + px * 128 + cs * 8);
      }
      short8 wfr[6];
      int kqg = half * 4 + kq;
#pragma unroll
      for (int t = 0; t < 6; ++t)
        wfr[t] = *(const short8*)(Wf + ((size_t)((hg * 8 + kqg) * 6 + t) * 64 + lane) * 8);
#pragma unroll
      for (int pt = 0; pt < 4; ++pt){
        aqT[0][pt] = MFMA16(wfr[0], xf[pt], aqT[0][pt]);   // D[ch][px]
        aqT[1][pt] = MFMA16(wfr[1], xf[pt], aqT[1][pt]);
        akT[0][pt] = MFMA16(wfr[2], xf[pt], akT[0][pt]);
        akT[1][pt] = MFMA16(wfr[3], xf[pt], akT[1][pt]);
        avN[pt][0] = MFMA16(xf[pt], wfr[4], avN[pt][0]);   // D[px][ch]
        avN[pt][1] = MFMA16(xf[pt], wfr[5], avN[pt][1]);
      }
    }
    if (half == 0){
      asm volatile("s_waitcnt vmcnt(0)" ::: "memory");  // own x1 DMAs landed
      __builtin_amdgcn_s_barrier();                     // all waves' x1 landed
    }
  }
  __syncthreads();                           // all x reads done -> x0/x1 become vT/q

  // write q,k -> [px][128ch swz], b64-packed (lane rows = 4 consecutive ch)
#pragma unroll
  for (int t = 0; t < 2; ++t)
#pragma unroll
    for (int pt = 0; pt < 4; ++pt){
      int px = pt * 16 + (lane & 15);
      int ck = hl * 4 + t * 2 + ((lane >> 4) >> 1);     // chl>>3, const over j
      int sub = ((lane >> 4) & 1) * 4;                  // chl&7 base
      int pos = px * 128 + (((ck & 8) | ((ck ^ px) & 7)) << 3) + sub;
      *(unsigned long long*)(lds + 8192 + pos)  = pack4(aqT[t][pt]);   // over x1
      *(unsigned long long*)(lds + 16384 + pos) = pack4(akT[t][pt]);
    }
  // write vT -> x0 region [128ch][64px swz], b64-packed (lane rows = 4 consecutive px)
#pragma unroll
  for (int ct = 0; ct < 2; ++ct)
#pragma unroll
    for (int pt = 0; pt < 4; ++pt){
      int chl = hl * 32 + ct * 16 + (lane & 15);
      int pxb = pt * 16 + ((lane >> 4) << 2);
      int addr = chl * 64 + (((pxb >> 3) ^ (chl & 7)) << 3) + (pxb & 7);
      *(unsigned long long*)(lds + addr) = pack4(avN[pt][ct]);
    }

  // ---- phase 2: S^T = K * Q^T (own head's q,k -- written by THIS wave, in-order LDS) ----
  short8 kf[4], qf[4];
#pragma unroll
  for (int i = 0; i < 4; ++i){
    int px = i * 16 + (lane & 15);
    int c = hl * 4 + (lane >> 4);            // own head's chunks
    int cs = (c & 8) | ((c ^ px) & 7);
    qf[i] = *(const short8*)(lds + 8192 + px * 128 + cs * 8);
    kf[i] = *(const short8*)(lds + 16384 + px * 128 + cs * 8);
  }
  f32x4 s[4][4] = {};
#pragma unroll
  for (int mi = 0; mi < 4; ++mi)
#pragma unroll
    for (int ni = 0; ni < 4; ++ni)
      s[mi][ni] = MFMA16(kf[mi], qf[ni], s[mi][ni]);
  __syncthreads();                           // all q/k reads + vT writes visible; q+k -> sP

  // ---- softmax over k' per q column; P b64-packed to own sP ----
  const float cexp = 0.25504437f;            // log2(e)/sqrt(32)
  unsigned short* sP = lds + 8192 + hl * 4096;
  bool q0 = (lane < 16);
#pragma unroll
  for (int ni = 0; ni < 4; ++ni){
    float m = s[0][ni][0];
#pragma unroll
    for (int mi = 0; mi < 3; ++mi)
#pragma unroll
      for (int r = 0; r < 4; ++r)
        if (mi | r) m = fmaxf(m, s[mi][ni][r]);
    m = fmaxf(m, q0 ? s[3][ni][0] : -3.0e38f);
    m = fmaxf(m, __shfl_xor(m, 16));
    m = fmaxf(m, __shfl_xor(m, 32));
    float sum = 0.f;
    float pv[4][4];
#pragma unroll
    for (int mi = 0; mi < 3; ++mi)
#pragma unroll
      for (int r = 0; r < 4; ++r){
        float e2 = exp2f((s[mi][ni][r] - m) * cexp);
        pv[mi][r] = e2; sum += e2;
      }
    {
      float e2 = q0 ? exp2f((s[3][ni][0] - m) * cexp) : 0.f;
      pv[3][0] = e2; sum += e2;
      pv[3][1] = 0.f; pv[3][2] = 0.f; pv[3][3] = 0.f;
    }
    sum += __shfl_xor(sum, 16);
    sum += __shfl_xor(sum, 32);
    float inv = 1.0f / sum;
    int q = ni * 16 + (lane & 15);
#pragma unroll
    for (int mi = 0; mi < 4; ++mi){
      int kpb2 = mi * 32 + ((lane >> 4) << 3);          // byte offset of 4-kp group
      int bo = (q * 128 + kpb2) ^ ((q & 7) << 4);
      unsigned long long pk =
          (unsigned long long)pk2(pv[mi][0] * inv, pv[mi][1] * inv)
        | ((unsigned long long)pk2(pv[mi][2] * inv, pv[mi][3] * inv) << 32);
      *(unsigned long long*)((char*)sP + bo) = pk;
    }
  }

  // ---- phase 3: O^T = V^T * P^T (own sP + own vT rows); D[ch][q] ----
  f32x4 oT[2][4] = {};
#pragma unroll
  for (int kc = 0; kc < 2; ++kc){
    short8 pa[4], vb[2];
#pragma unroll
    for (int mtp = 0; mtp < 4; ++mtp){
      int row = mtp * 16 + (lane & 15);
      int bo = (row * 128 + kc * 64 + (lane >> 4) * 16) ^ ((row & 7) << 4);
      pa[mtp] = *(const short8*)((char*)sP + bo);
    }
#pragma unroll
    for (int ntp = 0; ntp < 2; ++ntp){
      int chl = hl * 32 + ntp * 16 + (lane & 15);
      int k0 = kc * 32 + (lane >> 4) * 8;
      vb[ntp] = *(const short8*)(lds + chl * 64 + (((k0 >> 3) ^ (chl & 7)) << 3));
    }
#pragma unroll
    for (int mtp = 0; mtp < 4; ++mtp)
#pragma unroll
      for (int ntp = 0; ntp < 2; ++ntp)
        oT[ntp][mtp] = MFMA16(vb[ntp], pa[mtp], oT[ntp][mtp]);
  }
  // O -> own sP area [64px(q)][32ch swz], b64-packed (lane rows = 4 consecutive ch)
#pragma unroll
  for (int ntp = 0; ntp < 2; ++ntp)
#pragma unroll
    for (int mtp = 0; mtp < 4; ++mtp){
      int px = mtp * 16 + (lane & 15);
      int chb = ntp * 16 + ((lane >> 4) << 2);
      int c2 = chb >> 3;
      int addr = px * 32 + (((c2 ^ px) & 3) << 3) + (chb & 7);
      *(unsigned long long*)(sP + addr) = pack4(oT[ntp][mtp]);
    }
  __syncthreads();

  // ---- phase 4: cooperative 16B panel stores (this block's 4 heads) ----
  size_t pb0 = (size_t)b * 392 * 4;
#pragma unroll
  for (int it = 0; it < 4; ++it){
    int id = it * 256 + tid;                 // 0..1023 = 64px * 16 chunks
    int px = id >> 4, ck = id & 15;
    if (px < 49){
      int hl2 = ck >> 2, c2 = ck & 3;
      short8 v = *(const short8*)(lds + 8192 + hl2 * 4096 + px * 32 + (((c2 ^ px) & 3) << 3));
      int ch0 = (hh * 4 + hl2) * 32 + c2 * 8;
      int pg = (wh * 7 + px / 7) * 224 + ww * 7 + px % 7;
      int nt = pg >> 7, pr = pg & 127;
      size_t off = (pb0 + (size_t)nt * 4 + (ch0 >> 6)) * 8192 + panel_off(pr, ch0 & 63);
      *(short8*)(attnP + off) = v;
    }
  }
}

// ---------------- GEMM out + residual (bf16 y) + per-block BN partials ----------------
// counted-vmcnt 2-deep pipeline: next tile's 8 loads stay in flight across barriers
__global__ __launch_bounds__(256) void k_gemm_out(const unsigned short* __restrict__ Wp,
                                                  const unsigned short* __restrict__ Bp,
                                                  const float* __restrict__ x,
                                                  unsigned short* __restrict__ ybf,
                                                  float* __restrict__ partials){
  int bid = blockIdx.x;
  int wg = (bid & 7) * 392 + (bid >> 3);     // 3136 = 8*392
  int mt = wg & 1; int rest = wg >> 1;       // mt fastest
  int nt = rest % 392; int b = rest / 392;

  __shared__ __align__(16) unsigned short lds[32768];  // dbuf (2 x 32KB)

  int tid = threadIdx.x;
  int lane = tid & 63;
  int wave = tid >> 6;
  int wm = wave >> 1, wn = wave & 1;

  const unsigned short* Apan = Wp + (size_t)mt * 4 * 8192;
  const unsigned short* Bpan = Bp + ((size_t)(b * 392 + nt)) * 4 * 8192;

  int aoff[2][4], boff[2][4];
#pragma unroll
  for (int kk = 0; kk < 2; ++kk)
#pragma unroll
    for (int i = 0; i < 4; ++i){
      int rowA = wm * 64 + i * 16 + (lane & 15);
      aoff[kk][i] = rowA * 64 + (((kk * 4 + (lane >> 4)) ^ (rowA & 7)) << 3);
      int rowB = wn * 64 + i * 16 + (lane & 15);
      boff[kk][i] = rowB * 64 + (((kk * 4 + (lane >> 4)) ^ (rowB & 7)) << 3);
    }
  int cb = wave * 2048;
  f32x4 acc[4][4] = {};

  // prologue: T0 -> buf0, T1 -> buf1 (16 loads in flight per wave)
#pragma unroll
  for (int j = 0; j < 4; ++j){
    int o2 = cb + j * 512;
    GLL16(Apan + o2 + lane * 8, lds + o2);
    GLL16(Bpan + o2 + lane * 8, lds + 8192 + o2);
  }
#pragma unroll
  for (int j = 0; j < 4; ++j){
    int o2 = cb + j * 512;
    GLL16(Apan + 8192 + o2 + lane * 8, lds + 16384 + o2);
    GLL16(Bpan + 8192 + o2 + lane * 8, lds + 24576 + o2);
  }

  int cur = 0;
  for (int kq = 0; kq < 4; ++kq){
    if (kq < 3) asm volatile("s_waitcnt vmcnt(8)" ::: "memory");  // tile kq landed; next stays in flight
    else        asm volatile("s_waitcnt vmcnt(0)" ::: "memory");
    __builtin_amdgcn_s_barrier();
    const unsigned short* Alds = lds + cur * 16384;
    const unsigned short* Blds = Alds + 8192;
#pragma unroll
    for (int kk = 0; kk < 2; ++kk){
      short8 af[4], bfv[4];
#pragma unroll
      for (int i = 0; i < 4; ++i) af[i]  = *(const short8*)(Alds + aoff[kk][i]);
#pragma unroll
      for (int j = 0; j < 4; ++j) bfv[j] = *(const short8*)(Blds + boff[kk][j]);
#pragma unroll
      for (int i = 0; i < 4; ++i)
#pragma unroll
        for (int j = 0; j < 4; ++j)
          acc[i][j] = MFMA16(af[i], bfv[j], acc[i][j]);
    }
    asm volatile("s_waitcnt lgkmcnt(0)" ::: "memory");   // this wave's LDS reads consumed
    __builtin_amdgcn_s_barrier();                        // all waves done reading buf[cur]
    if (kq < 2){
      const unsigned short* Ak = Apan + (kq + 2) * 8192;
      const unsigned short* Bk = Bpan + (kq + 2) * 8192;
      unsigned short* dst = lds + cur * 16384;
#pragma unroll
      for (int j = 0; j < 4; ++j){
        int o2 = cb + j * 512;
        GLL16(Ak + o2 + lane * 8, dst + o2);
        GLL16(Bk + o2 + lane * 8, dst + 8192 + o2);
      }
    }
    cur ^= 1;
  }
  // epilogue: residual add, bf16 y store, per-channel partial sums
  float ps[4][4] = {}, pq[4][4] = {};
#pragma unroll
  for (int i = 0; i < 4; ++i)
#pragma unroll
    for (int j = 0; j < 4; ++j){
      int o = mt * 128 + wm * 64 + i * 16 + (lane >> 4) * 4;
      int p = nt * 128 + wn * 64 + j * 16 + (lane & 15);
      size_t base = ((size_t)(b * 256 + o)) * HW_ + p;
#pragma unroll
      for (int r2 = 0; r2 < 4; ++r2){
        float v = acc[i][j][r2] + x[base + (size_t)r2 * HW_];
        ybf[base + (size_t)r2 * HW_] = f2bf(v);
        ps[i][r2] += v;
        pq[i][r2] += v * v;
      }
    }
  float* fl = (float*)lds;    // [wn 2][cl 128] sums, +256 sq
#pragma unroll
  for (int i = 0; i < 4; ++i)
#pragma unroll
    for (int r2 = 0; r2 < 4; ++r2){
      float a = ps[i][r2], q2 = pq[i][r2];
      a += __shfl_xor(a, 1);  q2 += __shfl_xor(q2, 1);
      a += __shfl_xor(a, 2);  q2 += __shfl_xor(q2, 2);
      a += __shfl_xor(a, 4);  q2 += __shfl_xor(q2, 4);
      a += __shfl_xor(a, 8);  q2 += __shfl_xor(q2, 8);
      if ((lane & 15) == 0){
        int cl = wm * 64 + i * 16 + (lane >> 4) * 4 + r2;
        fl[wn * 128 + cl] = a;
        fl[256 + wn * 128 + cl] = q2;
      }
    }
  __syncthreads();
  if (tid < 128){
    partials[(size_t)wg * 256 + tid]       = fl[tid] + fl[128 + tid];
    partials[(size_t)wg * 256 + 128 + tid] = fl[256 + tid] + fl[384 + tid];
  }
}

// ---------------- reduce per-block partials -> mean / rsqrt ----------------
__global__ __launch_bounds__(256) void k_stats2(const float* __restrict__ partials, float* __restrict__ stats){
  int c = blockIdx.x;           // 0..255
  int mt = c >> 7, cl = c & 127;
  int t = threadIdx.x;
  float s = 0.f, q = 0.f;
  for (int idx = t; idx < 1568; idx += 256){
    const float* p = partials + (size_t)(2 * idx + mt) * 256;
    s += p[cl]; q += p[128 + cl];
  }
  __shared__ float r1[256], r2[256];
  r1[t] = s; r2[t] = q; __syncthreads();
  for (int off = 128; off > 0; off >>= 1){
    if (t < off){ r1[t] += r1[t + off]; r2[t] += r2[t + off]; }
    __syncthreads();
  }
  if (t == 0){
    float mean = r1[0] * (1.f / 200704.f);
    float var  = r2[0] * (1.f / 200704.f) - mean * mean;
    stats[c] = mean;
    stats[256 + c] = rsqrtf(var + 1e-5f);
  }
}

// ---------------- normalize: bf16 y -> fp32 out ----------------
__global__ __launch_bounds__(256) void k_norm(const unsigned short* __restrict__ ybf,
                                              const float* __restrict__ stats,
                                              const float* __restrict__ gamma, const float* __restrict__ beta,
                                              float* __restrict__ out){
  const long long total = 6422528LL;   // 51380224 / 8
  for (long long idx = (long long)blockIdx.x * 256 + threadIdx.x; idx < total; idx += (long long)gridDim.x * 256){
    int c = (int)((idx / 6272) & 255);  // 6272 = 50176/8
    float sc = stats[256 + c] * gamma[c];
    float sh = beta[c] - stats[c] * sc;
    short8 v = *(const short8*)(ybf + idx * 8);
    float4 o0, o1;
    o0.x = bf2f((unsigned short)v[0]) * sc + sh;
    o0.y = bf2f((unsigned short)v[1]) * sc + sh;
    o0.z = bf2f((unsigned short)v[2]) * sc + sh;
    o0.w = bf2f((unsigned short)v[3]) * sc + sh;
    o1.x = bf2f((unsigned short)v[4]) * sc + sh;
    o1.y = bf2f((unsigned short)v[5]) * sc + sh;
    o1.z = bf2f((unsigned short)v[6]) * sc + sh;
    o1.w = bf2f((unsigned short)v[7]) * sc + sh;
    *(float4*)(out + idx * 8)     = o0;
    *(float4*)(out + idx * 8 + 4) = o1;
  }
}

extern "C" void kernel_launch(void* const* d_in, const int* in_sizes, int n_in,
                              void* d_out, int out_size, void* d_ws, size_t ws_size,
                              hipStream_t stream){
  const float* x     = (const float*)d_in[0];
  const float* Wq    = (const float*)d_in[1];
  const float* Wk    = (const float*)d_in[2];
  const float* Wv    = (const float*)d_in[3];
  const float* Wo    = (const float*)d_in[4];
  const float* gamma = (const float*)d_in[5];
  const float* beta  = (const float*)d_in[6];
  float* out = (float*)d_out;

  char* ws = (char*)d_ws;
  unsigned short* Wf     = (unsigned short*)ws;                               // 393216 B
  unsigned short* Wo_b   = (unsigned short*)(ws + 393216);                    // 131072 B
  float*          stats  = (float*)(ws + 524288);                             // 2048 B
  unsigned short* xw     = (unsigned short*)(ws + 1048576);                   // 134217728 B
  unsigned short* attnP  = (unsigned short*)(ws + 1048576 + 134217728);       // 102760448 B
  float*          partials = (float*)(ws + 1048576 + 134217728 + 102760448);  // 3211264 B
  unsigned short* ybf    = xw;   // alias: xw dead after k_fused (stream-ordered)

  k_convw<<<128, 256, 0, stream>>>(Wq, Wk, Wv, Wo, Wf, Wo_b);
  k_xw<<<2048, 256, 0, stream>>>(x, xw);
  k_fused<<<8192, 256, 0, stream>>>(xw, Wf, attnP);
  k_gemm_out<<<3136, 256, 0, stream>>>(Wo_b, attnP, x, ybf, partials);
  k_stats2<<<256, 256, 0, stream>>>(partials, stats);
  k_norm<<<4096, 256, 0, stream>>>(ybf, stats, gamma, beta, out);
}

// Round 14
// 463.588 us; speedup vs baseline: 1.0296x; 1.0296x over previous
//
#include <hip/hip_runtime.h>
#include <stdint.h>

typedef __attribute__((ext_vector_type(8))) short short8;
typedef __attribute__((ext_vector_type(4))) float f32x4;

#define MFMA16(a,b,c) __builtin_amdgcn_mfma_f32_16x16x32_bf16((a),(b),(c),0,0,0)

// async global->LDS DMA, 16B per lane; LDS dest = wave-uniform base + lane*16B
#define GLL16(g, l) __builtin_amdgcn_global_load_lds( \
    (const __attribute__((address_space(1))) void*)(g), \
    (__attribute__((address_space(3))) void*)(l), 16, 0, 0)

__device__ __forceinline__ unsigned short f2bf(float f){
  unsigned u = __builtin_bit_cast(unsigned, f);
  u += 0x7fffu + ((u >> 16) & 1u);
  return (unsigned short)(u >> 16);
}
__device__ __forceinline__ float bf2f(unsigned short s){
  unsigned u = ((unsigned)s) << 16;
  return __builtin_bit_cast(float, u);
}
// pack 4 f32 -> 4 bf16 in a u64 (RNE, proven f2bf path)
__device__ __forceinline__ unsigned long long pack4(f32x4 v){
  return (unsigned long long)f2bf(v[0])
       | ((unsigned long long)f2bf(v[1]) << 16)
       | ((unsigned long long)f2bf(v[2]) << 32)
       | ((unsigned long long)f2bf(v[3]) << 48);
}

static constexpr int HW_ = 50176;   // 224*224

// offset of element (row r 0..127, k c64 0..63) inside one 8192-elem panel,
// XOR-swizzled so ds_read_b128 of a 16-lane column slice is conflict-free
__device__ __forceinline__ int panel_off(int r, int c64){
  return r * 64 + ((((c64 >> 3) ^ (r & 7))) << 3) + (c64 & 7);
}

// ---------------- weights fp32 -> bf16 ----------------
__global__ __launch_bounds__(256) void k_convw(const float* __restrict__ Wq, const float* __restrict__ Wk,
                        const float* __restrict__ Wv, const float* __restrict__ Wo,
                        unsigned short* __restrict__ Wf, unsigned short* __restrict__ Wob){
  int gid = blockIdx.x * 256 + threadIdx.x;   // grid 128 -> 32768
  if (gid < 24576){
    int lane = gid & 63;
    int r1 = gid >> 6;          // 0..383
    int t = r1 % 6;
    int r2 = r1 / 6;            // 0..63
    int kq = r2 & 7, hh = r2 >> 3;
    const float* W = (t < 2) ? Wq : (t < 4) ? Wk : Wv;
    int ch = hh * 32 + (t & 1) * 16 + (lane & 15);
    int k0 = kq * 32 + (lane >> 4) * 8;
    const float* src = W + ch * 256 + k0;
    float4 a = *(const float4*)src, b2 = *(const float4*)(src + 4);
    short8 v;
    v[0]=f2bf(a.x); v[1]=f2bf(a.y); v[2]=f2bf(a.z); v[3]=f2bf(a.w);
    v[4]=f2bf(b2.x); v[5]=f2bf(b2.y); v[6]=f2bf(b2.z); v[7]=f2bf(b2.w);
    *(short8*)(Wf + (size_t)gid * 8) = v;
  } else {
    int og = gid - 24576;       // 0..8191
    int o = og >> 5, ck = og & 31;
    const float* src = Wo + o * 256 + ck * 8;
    float4 a = *(const float4*)src, b2 = *(const float4*)(src + 4);
    short8 v;
    v[0]=f2bf(a.x); v[1]=f2bf(a.y); v[2]=f2bf(a.z); v[3]=f2bf(a.w);
    v[4]=f2bf(b2.x); v[5]=f2bf(b2.y); v[6]=f2bf(b2.z); v[7]=f2bf(b2.w);
    int kq = ck >> 3;
    int off = panel_off(o & 127, (ck & 7) * 8);
    *(short8*)(Wob + ((o >> 7) * 4 + kq) * 8192 + off) = v;
  }
}

// ---------------- x (B,C,H,W) f32 -> xw[win][half 2][px 49/64][128c swz] bf16 ----------------
__global__ __launch_bounds__(256) void k_xw(const float* __restrict__ x, unsigned short* __restrict__ xw){
  int bid = blockIdx.x;
  int cq = bid & 15, wh = (bid >> 4) & 31, b = bid >> 9;
  __shared__ __align__(16) unsigned short tile[25088];  // 49 KB
  int tid = threadIdx.x;
  for (int it = 0; it < 25; ++it){
    int idx = it * 256 + tid;
    if (idx < 6272){
      int c = idx & 15;
      int t2 = idx >> 4;                  // 0..391
      int r = t2 / 56;
      int w4 = t2 % 56;
      float4 v = *(const float4*)(x + ((size_t)(b * 256 + cq * 16 + c)) * HW_ + (wh * 7 + r) * 224 + w4 * 4);
      float vv[4] = {v.x, v.y, v.z, v.w};
      int w0 = w4 * 4;
      int ww = w0 / 7;
      int cl = w0 % 7;
#pragma unroll
      for (int i = 0; i < 4; ++i){
        int px = r * 7 + cl;
        tile[ww * 784 + px * 16 + (((c >> 3) ^ (px & 1)) << 3) + (c & 7)] = f2bf(vv[i]);
        if (++cl == 7){ cl = 0; ++ww; }
      }
    }
  }
  __syncthreads();
  size_t wb = ((size_t)(b * 1024 + wh * 32)) * 16384;
  for (int it = 0; it < 13; ++it){
    int id = it * 256 + tid;
    if (id < 3136){                       // 32 ww x 49 px x 2 chunk-slots
      int ww = id / 98;
      int rem = id - ww * 98;
      int px = rem >> 1, hb = rem & 1;
      short8 v = *(const short8*)(tile + ww * 784 + px * 16 + ((hb ^ (px & 1)) << 3));
      int cc = cq * 2 + hb;               // global 8-ch chunk 0..31
      int half = cc >> 4, c4 = cc & 15;
      int pos = (c4 & 8) | ((c4 ^ px) & 7);
      *(short8*)(xw + wb + (size_t)ww * 16384 + half * 8192 + px * 128 + pos * 8) = v;
    }
  }
}

// ---------------- fused: qkv GEMM + window attention ----------------
// block = (window, 4-head half), 4 waves = 4 heads, 48 KB LDS -> 3 blocks/CU
// x0 at [0,8192), x1 at [8192,16384) (overlapped DMA, counted vmcnt);
// q overwrites x1, vT overwrites x0 after a single post-phase-1 barrier.
__global__ __launch_bounds__(256, 3) void k_fused(const unsigned short* __restrict__ xw,
                                                  const unsigned short* __restrict__ Wf,
                                                  unsigned short* __restrict__ attnP){
  int bid = blockIdx.x;
  int wg = (bid & 7) * 1024 + (bid >> 3);   // 8192 = 8*1024; window pair on same XCD
  int hh = wg & 1; int win = wg >> 1;
  int b = win >> 10;
  int wh = (win >> 5) & 31, ww = win & 31;
  int tid = threadIdx.x;
  int lane = tid & 63;
  int hl = tid >> 6;                         // local head 0..3
  int hg = hh * 4 + hl;                      // global head

  __shared__ __align__(16) unsigned short lds[24576];   // 48 KB

  const unsigned short* xwin = xw + (size_t)win * 16384;

  // ---- phase 0: zero pad rows 49..63 of BOTH x buffers + overlapped DMA ----
  if (tid < 240){
    int rr = 49 + (tid >> 4), ck = tid & 15;
    short8 z = {};
    *(short8*)(lds + rr * 128 + ck * 8) = z;
    *(short8*)(lds + 8192 + rr * 128 + ck * 8) = z;
  }
#pragma unroll
  for (int it = 0; it < 4; ++it){
    int chunk = it * 256 + tid;              // x half0 -> [0,8192)
    if (chunk < 784) GLL16(xwin + chunk * 8, lds + chunk * 8);
  }
#pragma unroll
  for (int it = 0; it < 4; ++it){
    int chunk = it * 256 + tid;              // x half1 -> [8192,16384), stays in flight
    if (chunk < 784) GLL16(xwin + 8192 + chunk * 8, lds + 8192 + chunk * 8);
  }
  if (hl == 0) asm volatile("s_waitcnt vmcnt(4) lgkmcnt(0)" ::: "memory");  // wave0: 4 x1 ops remain
  else         asm volatile("s_waitcnt vmcnt(3) lgkmcnt(0)" ::: "memory");  // waves1-3: 3 remain
  __builtin_amdgcn_s_barrier();              // x0 (and zero-fill) visible to all waves

  // ---- phase 1: qkv GEMM; q,k transposed (D[ch][px]); v natural (D[px][ch]) ----
  f32x4 aqT[2][4] = {}, akT[2][4] = {}, avN[4][2] = {};
  for (int half = 0; half < 2; ++half){
    const unsigned short* xb = lds + half * 8192;
    for (int kq = 0; kq < 4; ++kq){
      short8 xf[4];
#pragma unroll
      for (int pt = 0; pt < 4; ++pt){
        int px = pt * 16 + (lane & 15);
        int c = kq * 4 + (lane >> 4);        // chunk 0..15
        int cs = (c & 8) | ((c ^ px) & 7);
        xf[pt] = *(const short8*)(xb + px * 128 + cs * 8);
      }
      short8 wfr[6];
      int kqg = half * 4 + kq;
#pragma unroll
      for (int t = 0; t < 6; ++t)
        wfr[t] = *(const short8*)(Wf + ((size_t)((hg * 8 + kqg) * 6 + t) * 64 + lane) * 8);
#pragma unroll
      for (int pt = 0; pt < 4; ++pt){
        aqT[0][pt] = MFMA16(wfr[0], xf[pt], aqT[0][pt]);   // D[ch][px]
        aqT[1][pt] = MFMA16(wfr[1], xf[pt], aqT[1][pt]);
        akT[0][pt] = MFMA16(wfr[2], xf[pt], akT[0][pt]);
        akT[1][pt] = MFMA16(wfr[3], xf[pt], akT[1][pt]);
        avN[pt][0] = MFMA16(xf[pt], wfr[4], avN[pt][0]);   // D[px][ch]
        avN[pt][1] = MFMA16(xf[pt], wfr[5], avN[pt][1]);
      }
    }
    if (half == 0){
      asm volatile("s_waitcnt vmcnt(0)" ::: "memory");  // own x1 DMAs landed
      __builtin_amdgcn_s_barrier();                     // all waves' x1 landed
    }
  }
  __syncthreads();                           // all x reads done -> x0/x1 become vT/q

  // write q,k -> [px][128ch swz], b64-packed (lane rows = 4 consecutive ch)
#pragma unroll
  for (int t = 0; t < 2; ++t)
#pragma unroll
    for (int pt = 0; pt < 4; ++pt){
      int px = pt * 16 + (lane & 15);
      int ck = hl * 4 + t * 2 + ((lane >> 4) >> 1);     // chl>>3, const over j
      int sub = ((lane >> 4) & 1) * 4;                  // chl&7 base
      int pos = px * 128 + (((ck & 8) | ((ck ^ px) & 7)) << 3) + sub;
      *(unsigned long long*)(lds + 8192 + pos)  = pack4(aqT[t][pt]);   // over x1
      *(unsigned long long*)(lds + 16384 + pos) = pack4(akT[t][pt]);
    }
  // write vT -> x0 region [128ch][64px swz], b64-packed (lane rows = 4 consecutive px)
#pragma unroll
  for (int ct = 0; ct < 2; ++ct)
#pragma unroll
    for (int pt = 0; pt < 4; ++pt){
      int chl = hl * 32 + ct * 16 + (lane & 15);
      int pxb = pt * 16 + ((lane >> 4) << 2);
      int addr = chl * 64 + (((pxb >> 3) ^ (chl & 7)) << 3) + (pxb & 7);
      *(unsigned long long*)(lds + addr) = pack4(avN[pt][ct]);
    }

  // ---- phase 2: S^T = K * Q^T (own head's q,k -- written by THIS wave, in-order LDS) ----
  short8 kf[4], qf[4];
#pragma unroll
  for (int i = 0; i < 4; ++i){
    int px = i * 16 + (lane & 15);
    int c = hl * 4 + (lane >> 4);            // own head's chunks
    int cs = (c & 8) | ((c ^ px) & 7);
    qf[i] = *(const short8*)(lds + 8192 + px * 128 + cs * 8);
    kf[i] = *(const short8*)(lds + 16384 + px * 128 + cs * 8);
  }
  f32x4 s[4][4] = {};
#pragma unroll
  for (int mi = 0; mi < 4; ++mi)
#pragma unroll
    for (int ni = 0; ni < 4; ++ni)
      s[mi][ni] = MFMA16(kf[mi], qf[ni], s[mi][ni]);
  __syncthreads();                           // all q/k reads + vT writes visible; q+k -> sP

  // ---- softmax over k' per q column; P b64-packed to own sP ----
  const float cexp = 0.25504437f;            // log2(e)/sqrt(32)
  unsigned short* sP = lds + 8192 + hl * 4096;
  bool q0 = (lane < 16);
#pragma unroll
  for (int ni = 0; ni < 4; ++ni){
    float m = s[0][ni][0];
#pragma unroll
    for (int mi = 0; mi < 3; ++mi)
#pragma unroll
      for (int r = 0; r < 4; ++r)
        if (mi | r) m = fmaxf(m, s[mi][ni][r]);
    m = fmaxf(m, q0 ? s[3][ni][0] : -3.0e38f);
    m = fmaxf(m, __shfl_xor(m, 16));
    m = fmaxf(m, __shfl_xor(m, 32));
    float sum = 0.f;
    float pv[4][4];
#pragma unroll
    for (int mi = 0; mi < 3; ++mi)
#pragma unroll
      for (int r = 0; r < 4; ++r){
        float e2 = exp2f((s[mi][ni][r] - m) * cexp);
        pv[mi][r] = e2; sum += e2;
      }
    {
      float e2 = q0 ? exp2f((s[3][ni][0] - m) * cexp) : 0.f;
      pv[3][0] = e2; sum += e2;
      pv[3][1] = 0.f; pv[3][2] = 0.f; pv[3][3] = 0.f;
    }
    sum += __shfl_xor(sum, 16);
    sum += __shfl_xor(sum, 32);
    float inv = 1.0f / sum;
    int q = ni * 16 + (lane & 15);
#pragma unroll
    for (int mi = 0; mi < 4; ++mi){
      int kpb2 = mi * 32 + ((lane >> 4) << 3);          // byte offset of 4-kp group
      int bo = (q * 128 + kpb2) ^ ((q & 7) << 4);
      unsigned long long pk =
          (unsigned long long)f2bf(pv[mi][0] * inv)
        | ((unsigned long long)f2bf(pv[mi][1] * inv) << 16)
        | ((unsigned long long)f2bf(pv[mi][2] * inv) << 32)
        | ((unsigned long long)f2bf(pv[mi][3] * inv) << 48);
      *(unsigned long long*)((char*)sP + bo) = pk;
    }
  }

  // ---- phase 3: O^T = V^T * P^T (own sP + own vT rows); D[ch][q] ----
  f32x4 oT[2][4] = {};
#pragma unroll
  for (int kc = 0; kc < 2; ++kc){
    short8 pa[4], vb[2];
#pragma unroll
    for (int mtp = 0; mtp < 4; ++mtp){
      int row = mtp * 16 + (lane & 15);
      int bo = (row * 128 + kc * 64 + (lane >> 4) * 16) ^ ((row & 7) << 4);
      pa[mtp] = *(const short8*)((char*)sP + bo);
    }
#pragma unroll
    for (int ntp = 0; ntp < 2; ++ntp){
      int chl = hl * 32 + ntp * 16 + (lane & 15);
      int k0 = kc * 32 + (lane >> 4) * 8;
      vb[ntp] = *(const short8*)(lds + chl * 64 + (((k0 >> 3) ^ (chl & 7)) << 3));
    }
#pragma unroll
    for (int mtp = 0; mtp < 4; ++mtp)
#pragma unroll
      for (int ntp = 0; ntp < 2; ++ntp)
        oT[ntp][mtp] = MFMA16(vb[ntp], pa[mtp], oT[ntp][mtp]);
  }
  // O -> own sP area [64px(q)][32ch swz], b64-packed (lane rows = 4 consecutive ch)
#pragma unroll
  for (int ntp = 0; ntp < 2; ++ntp)
#pragma unroll
    for (int mtp = 0; mtp < 4; ++mtp){
      int px = mtp * 16 + (lane & 15);
      int chb = ntp * 16 + ((lane >> 4) << 2);
      int c2 = chb >> 3;
      int addr = px * 32 + (((c2 ^ px) & 3) << 3) + (chb & 7);
      *(unsigned long long*)(sP + addr) = pack4(oT[ntp][mtp]);
    }
  __syncthreads();

  // ---- phase 4: cooperative 16B panel stores (this block's 4 heads) ----
  size_t pb0 = (size_t)b * 392 * 4;
#pragma unroll
  for (int it = 0; it < 4; ++it){
    int id = it * 256 + tid;                 // 0..1023 = 64px * 16 chunks
    int px = id >> 4, ck = id & 15;
    if (px < 49){
      int hl2 = ck >> 2, c2 = ck & 3;
      short8 v = *(const short8*)(lds + 8192 + hl2 * 4096 + px * 32 + (((c2 ^ px) & 3) << 3));
      int ch0 = (hh * 4 + hl2) * 32 + c2 * 8;
      int pg = (wh * 7 + px / 7) * 224 + ww * 7 + px % 7;
      int nt = pg >> 7, pr = pg & 127;
      size_t off = (pb0 + (size_t)nt * 4 + (ch0 >> 6)) * 8192 + panel_off(pr, ch0 & 63);
      *(short8*)(attnP + off) = v;
    }
  }
}

// ---------------- GEMM out + residual (bf16 y) + per-block BN partials ----------------
// 8 waves (2 wm x 4 wn), 64x32 per wave; counted-vmcnt 2-deep pipeline
__global__ __launch_bounds__(512) void k_gemm_out(const unsigned short* __restrict__ Wp,
                                                  const unsigned short* __restrict__ Bp,
                                                  const float* __restrict__ x,
                                                  unsigned short* __restrict__ ybf,
                                                  float* __restrict__ partials){
  int bid = blockIdx.x;
  int wg = (bid & 7) * 392 + (bid >> 3);     // 3136 = 8*392
  int mt = wg & 1; int rest = wg >> 1;       // mt fastest
  int nt = rest % 392; int b = rest / 392;

  __shared__ __align__(16) unsigned short lds[32768];  // dbuf (2 x 32KB)

  int tid = threadIdx.x;
  int lane = tid & 63;
  int wave = tid >> 6;                        // 0..7
  int wm = wave >> 2, wn = wave & 3;          // 2 x 4

  const unsigned short* Apan = Wp + (size_t)mt * 4 * 8192;
  const unsigned short* Bpan = Bp + ((size_t)(b * 392 + nt)) * 4 * 8192;

  int aoff[2][4], boff[2][2];
#pragma unroll
  for (int kk = 0; kk < 2; ++kk){
#pragma unroll
    for (int i = 0; i < 4; ++i){
      int rowA = wm * 64 + i * 16 + (lane & 15);
      aoff[kk][i] = rowA * 64 + (((kk * 4 + (lane >> 4)) ^ (rowA & 7)) << 3);
    }
#pragma unroll
    for (int j = 0; j < 2; ++j){
      int rowB = wn * 32 + j * 16 + (lane & 15);
      boff[kk][j] = rowB * 64 + (((kk * 4 + (lane >> 4)) ^ (rowB & 7)) << 3);
    }
  }
  int cb = wave * 1024;                       // per-wave staging region (elems)
  f32x4 acc[4][2] = {};

  // prologue: T0 -> buf0, T1 -> buf1 (8 loads in flight per wave, FIFO tile order)
#pragma unroll
  for (int t = 0; t < 2; ++t)
#pragma unroll
    for (int j2 = 0; j2 < 2; ++j2){
      int o2 = cb + j2 * 512;
      GLL16(Apan + t * 8192 + o2 + lane * 8, lds + t * 16384 + o2);
      GLL16(Bpan + t * 8192 + o2 + lane * 8, lds + t * 16384 + 8192 + o2);
    }

  int cur = 0;
  for (int kq = 0; kq < 4; ++kq){
    if (kq < 3) asm volatile("s_waitcnt vmcnt(4)" ::: "memory");  // tile kq landed; next in flight
    else        asm volatile("s_waitcnt vmcnt(0)" ::: "memory");
    __builtin_amdgcn_s_barrier();
    const unsigned short* Alds = lds + cur * 16384;
    const unsigned short* Blds = Alds + 8192;
#pragma unroll
    for (int kk = 0; kk < 2; ++kk){
      short8 af[4], bfv[2];
#pragma unroll
      for (int i = 0; i < 4; ++i) af[i]  = *(const short8*)(Alds + aoff[kk][i]);
#pragma unroll
      for (int j = 0; j < 2; ++j) bfv[j] = *(const short8*)(Blds + boff[kk][j]);
#pragma unroll
      for (int i = 0; i < 4; ++i)
#pragma unroll
        for (int j = 0; j < 2; ++j)
          acc[i][j] = MFMA16(af[i], bfv[j], acc[i][j]);
    }
    asm volatile("s_waitcnt lgkmcnt(0)" ::: "memory");   // this wave's LDS reads consumed
    __builtin_amdgcn_s_barrier();                        // all waves done reading buf[cur]
    if (kq < 2){
      const unsigned short* Ak = Apan + (kq + 2) * 8192;
      const unsigned short* Bk = Bpan + (kq + 2) * 8192;
      unsigned short* dst = lds + cur * 16384;
#pragma unroll
      for (int j2 = 0; j2 < 2; ++j2){
        int o2 = cb + j2 * 512;
        GLL16(Ak + o2 + lane * 8, dst + o2);
        GLL16(Bk + o2 + lane * 8, dst + 8192 + o2);
      }
    }
    cur ^= 1;
  }
  // epilogue: residual add, bf16 y store, per-channel partial sums
  float ps[4][4] = {}, pq[4][4] = {};
#pragma unroll
  for (int i = 0; i < 4; ++i)
#pragma unroll
    for (int j = 0; j < 2; ++j){
      int o = mt * 128 + wm * 64 + i * 16 + (lane >> 4) * 4;
      int p = nt * 128 + wn * 32 + j * 16 + (lane & 15);
      size_t base = ((size_t)(b * 256 + o)) * HW_ + p;
#pragma unroll
      for (int r2 = 0; r2 < 4; ++r2){
        float v = acc[i][j][r2] + x[base + (size_t)r2 * HW_];
        ybf[base + (size_t)r2 * HW_] = f2bf(v);
        ps[i][r2] += v;
        pq[i][r2] += v * v;
      }
    }
  float* fl = (float*)lds;    // [wn 4][cl 128] sums at 0, sq at +512
#pragma unroll
  for (int i = 0; i < 4; ++i)
#pragma unroll
    for (int r2 = 0; r2 < 4; ++r2){
      float a = ps[i][r2], q2 = pq[i][r2];
      a += __shfl_xor(a, 1);  q2 += __shfl_xor(q2, 1);
      a += __shfl_xor(a, 2);  q2 += __shfl_xor(q2, 2);
      a += __shfl_xor(a, 4);  q2 += __shfl_xor(q2, 4);
      a += __shfl_xor(a, 8);  q2 += __shfl_xor(q2, 8);
      if ((lane & 15) == 0){
        int cl = wm * 64 + i * 16 + (lane >> 4) * 4 + r2;
        fl[wn * 128 + cl] = a;
        fl[512 + wn * 128 + cl] = q2;
      }
    }
  __syncthreads();
  if (tid < 128){
    partials[(size_t)wg * 256 + tid] =
        fl[tid] + fl[128 + tid] + fl[256 + tid] + fl[384 + tid];
    partials[(size_t)wg * 256 + 128 + tid] =
        fl[512 + tid] + fl[640 + tid] + fl[768 + tid] + fl[896 + tid];
  }
}

// ---------------- reduce per-block partials -> mean / rsqrt ----------------
__global__ __launch_bounds__(256) void k_stats2(const float* __restrict__ partials, float* __restrict__ stats){
  int c = blockIdx.x;           // 0..255
  int mt = c >> 7, cl = c & 127;
  int t = threadIdx.x;
  float s = 0.f, q = 0.f;
  for (int idx = t; idx < 1568; idx += 256){
    const float* p = partials + (size_t)(2 * idx + mt) * 256;
    s += p[cl]; q += p[128 + cl];
  }
  __shared__ float r1[256], r2[256];
  r1[t] = s; r2[t] = q; __syncthreads();
  for (int off = 128; off > 0; off >>= 1){
    if (t < off){ r1[t] += r1[t + off]; r2[t] += r2[t + off]; }
    __syncthreads();
  }
  if (t == 0){
    float mean = r1[0] * (1.f / 200704.f);
    float var  = r2[0] * (1.f / 200704.f) - mean * mean;
    stats[c] = mean;
    stats[256 + c] = rsqrtf(var + 1e-5f);
  }
}

// ---------------- normalize: bf16 y -> fp32 out ----------------
__global__ __launch_bounds__(256) void k_norm(const unsigned short* __restrict__ ybf,
                                              const float* __restrict__ stats,
                                              const float* __restrict__ gamma, const float* __restrict__ beta,
                                              float* __restrict__ out){
  const long long total = 6422528LL;   // 51380224 / 8
  for (long long idx = (long long)blockIdx.x * 256 + threadIdx.x; idx < total; idx += (long long)gridDim.x * 256){
    int c = (int)((idx / 6272) & 255);  // 6272 = 50176/8
    float sc = stats[256 + c] * gamma[c];
    float sh = beta[c] - stats[c] * sc;
    short8 v = *(const short8*)(ybf + idx * 8);
    float4 o0, o1;
    o0.x = bf2f((unsigned short)v[0]) * sc + sh;
    o0.y = bf2f((unsigned short)v[1]) * sc + sh;
    o0.z = bf2f((unsigned short)v[2]) * sc + sh;
    o0.w = bf2f((unsigned short)v[3]) * sc + sh;
    o1.x = bf2f((unsigned short)v[4]) * sc + sh;
    o1.y = bf2f((unsigned short)v[5]) * sc + sh;
    o1.z = bf2f((unsigned short)v[6]) * sc + sh;
    o1.w = bf2f((unsigned short)v[7]) * sc + sh;
    *(float4*)(out + idx * 8)     = o0;
    *(float4*)(out + idx * 8 + 4) = o1;
  }
}

extern "C" void kernel_launch(void* const* d_in, const int* in_sizes, int n_in,
                              void* d_out, int out_size, void* d_ws, size_t ws_size,
                              hipStream_t stream){
  const float* x     = (const float*)d_in[0];
  const float* Wq    = (const float*)d_in[1];
  const float* Wk    = (const float*)d_in[2];
  const float* Wv    = (const float*)d_in[3];
  const float* Wo    = (const float*)d_in[4];
  const float* gamma = (const float*)d_in[5];
  const float* beta  = (const float*)d_in[6];
  float* out = (float*)d_out;

  char* ws = (char*)d_ws;
  unsigned short* Wf     = (unsigned short*)ws;                               // 393216 B
  unsigned short* Wo_b   = (unsigned short*)(ws + 393216);                    // 131072 B
  float*          stats  = (float*)(ws + 524288);                             // 2048 B
  unsigned short* xw     = (unsigned short*)(ws + 1048576);                   // 134217728 B
  unsigned short* attnP  = (unsigned short*)(ws + 1048576 + 134217728);       // 102760448 B
  float*          partials = (float*)(ws + 1048576 + 134217728 + 102760448);  // 3211264 B
  unsigned short* ybf    = xw;   // alias: xw dead after k_fused (stream-ordered)

  k_convw<<<128, 256, 0, stream>>>(Wq, Wk, Wv, Wo, Wf, Wo_b);
  k_xw<<<2048, 256, 0, stream>>>(x, xw);
  k_fused<<<8192, 256, 0, stream>>>(xw, Wf, attnP);
  k_gemm_out<<<3136, 512, 0, stream>>>(Wo_b, attnP, x, ybf, partials);
  k_stats2<<<256, 256, 0, stream>>>(partials, stats);
  k_norm<<<4096, 256, 0, stream>>>(ybf, stats, gamma, beta, out);
}

// Round 16
// 447.086 us; speedup vs baseline: 1.0676x; 1.0369x over previous
//
#include <hip/hip_runtime.h>
#include <stdint.h>

typedef __attribute__((ext_vector_type(8))) short short8;
typedef __attribute__((ext_vector_type(4))) float f32x4;

#define MFMA16(a,b,c) __builtin_amdgcn_mfma_f32_16x16x32_bf16((a),(b),(c),0,0,0)

// async global->LDS DMA, 16B per lane; LDS dest = wave-uniform base + lane*16B
#define GLL16(g, l) __builtin_amdgcn_global_load_lds( \
    (const __attribute__((address_space(1))) void*)(g), \
    (__attribute__((address_space(3))) void*)(l), 16, 0, 0)

__device__ __forceinline__ unsigned short f2bf(float f){
  unsigned u = __builtin_bit_cast(unsigned, f);
  u += 0x7fffu + ((u >> 16) & 1u);
  return (unsigned short)(u >> 16);
}
__device__ __forceinline__ float bf2f(unsigned short s){
  unsigned u = ((unsigned)s) << 16;
  return __builtin_bit_cast(float, u);
}
// pack 4 f32 -> 4 bf16 in a u64 (RNE, proven f2bf path)
__device__ __forceinline__ unsigned long long pack4(f32x4 v){
  return (unsigned long long)f2bf(v[0])
       | ((unsigned long long)f2bf(v[1]) << 16)
       | ((unsigned long long)f2bf(v[2]) << 32)
       | ((unsigned long long)f2bf(v[3]) << 48);
}

static constexpr int HW_ = 50176;   // 224*224

// offset of element (row r 0..127, k c64 0..63) inside one 8192-elem panel,
// XOR-swizzled so ds_read_b128 of a 16-lane column slice is conflict-free
__device__ __forceinline__ int panel_off(int r, int c64){
  return r * 64 + ((((c64 >> 3) ^ (r & 7))) << 3) + (c64 & 7);
}

// ---------------- weights fp32 -> bf16 ----------------
__global__ __launch_bounds__(256) void k_convw(const float* __restrict__ Wq, const float* __restrict__ Wk,
                        const float* __restrict__ Wv, const float* __restrict__ Wo,
                        unsigned short* __restrict__ Wf, unsigned short* __restrict__ Wob){
  int gid = blockIdx.x * 256 + threadIdx.x;   // grid 128 -> 32768
  if (gid < 24576){
    int lane = gid & 63;
    int r1 = gid >> 6;          // 0..383
    int t = r1 % 6;
    int r2 = r1 / 6;            // 0..63
    int kq = r2 & 7, hh = r2 >> 3;
    const float* W = (t < 2) ? Wq : (t < 4) ? Wk : Wv;
    int ch = hh * 32 + (t & 1) * 16 + (lane & 15);
    int k0 = kq * 32 + (lane >> 4) * 8;
    const float* src = W + ch * 256 + k0;
    float4 a = *(const float4*)src, b2 = *(const float4*)(src + 4);
    short8 v;
    v[0]=f2bf(a.x); v[1]=f2bf(a.y); v[2]=f2bf(a.z); v[3]=f2bf(a.w);
    v[4]=f2bf(b2.x); v[5]=f2bf(b2.y); v[6]=f2bf(b2.z); v[7]=f2bf(b2.w);
    *(short8*)(Wf + (size_t)gid * 8) = v;
  } else {
    int og = gid - 24576;       // 0..8191
    int o = og >> 5, ck = og & 31;
    const float* src = Wo + o * 256 + ck * 8;
    float4 a = *(const float4*)src, b2 = *(const float4*)(src + 4);
    short8 v;
    v[0]=f2bf(a.x); v[1]=f2bf(a.y); v[2]=f2bf(a.z); v[3]=f2bf(a.w);
    v[4]=f2bf(b2.x); v[5]=f2bf(b2.y); v[6]=f2bf(b2.z); v[7]=f2bf(b2.w);
    int kq = ck >> 3;
    int off = panel_off(o & 127, (ck & 7) * 8);
    *(short8*)(Wob + ((o >> 7) * 4 + kq) * 8192 + off) = v;
  }
}

// ---------------- x (B,C,H,W) f32 -> xw[win][half 2][px 49/64][128c swz] bf16 ----------------
__global__ __launch_bounds__(256) void k_xw(const float* __restrict__ x, unsigned short* __restrict__ xw){
  int bid = blockIdx.x;
  int cq = bid & 15, wh = (bid >> 4) & 31, b = bid >> 9;
  __shared__ __align__(16) unsigned short tile[25088];  // 49 KB
  int tid = threadIdx.x;
  for (int it = 0; it < 25; ++it){
    int idx = it * 256 + tid;
    if (idx < 6272){
      int c = idx & 15;
      int t2 = idx >> 4;                  // 0..391
      int r = t2 / 56;
      int w4 = t2 % 56;
      float4 v = *(const float4*)(x + ((size_t)(b * 256 + cq * 16 + c)) * HW_ + (wh * 7 + r) * 224 + w4 * 4);
      float vv[4] = {v.x, v.y, v.z, v.w};
      int w0 = w4 * 4;
      int ww = w0 / 7;
      int cl = w0 % 7;
#pragma unroll
      for (int i = 0; i < 4; ++i){
        int px = r * 7 + cl;
        tile[ww * 784 + px * 16 + (((c >> 3) ^ (px & 1)) << 3) + (c & 7)] = f2bf(vv[i]);
        if (++cl == 7){ cl = 0; ++ww; }
      }
    }
  }
  __syncthreads();
  size_t wb = ((size_t)(b * 1024 + wh * 32)) * 16384;
  for (int it = 0; it < 13; ++it){
    int id = it * 256 + tid;
    if (id < 3136){                       // 32 ww x 49 px x 2 chunk-slots
      int ww = id / 98;
      int rem = id - ww * 98;
      int px = rem >> 1, hb = rem & 1;
      short8 v = *(const short8*)(tile + ww * 784 + px * 16 + ((hb ^ (px & 1)) << 3));
      int cc = cq * 2 + hb;               // global 8-ch chunk 0..31
      int half = cc >> 4, c4 = cc & 15;
      int pos = (c4 & 8) | ((c4 ^ px) & 7);
      *(short8*)(xw + wb + (size_t)ww * 16384 + half * 8192 + px * 128 + pos * 8) = v;
    }
  }
}

// ---------------- fused: qkv GEMM + window attention ----------------
// block = (window, 4-head half), 4 waves = 4 heads, 48 KB LDS -> 3 blocks/CU
// x0 at [0,8192), x1 at [8192,16384) (overlapped DMA, counted vmcnt);
// q overwrites x1, vT overwrites x0 after a single post-phase-1 barrier.
__global__ __launch_bounds__(256, 3) void k_fused(const unsigned short* __restrict__ xw,
                                                  const unsigned short* __restrict__ Wf,
                                                  unsigned short* __restrict__ attnP){
  int bid = blockIdx.x;
  int wg = (bid & 7) * 1024 + (bid >> 3);   // 8192 = 8*1024; window pair on same XCD
  int hh = wg & 1; int win = wg >> 1;
  int b = win >> 10;
  int wh = (win >> 5) & 31, ww = win & 31;
  int tid = threadIdx.x;
  int lane = tid & 63;
  int hl = tid >> 6;                         // local head 0..3
  int hg = hh * 4 + hl;                      // global head

  __shared__ __align__(16) unsigned short lds[24576];   // 48 KB

  const unsigned short* xwin = xw + (size_t)win * 16384;

  // ---- phase 0: zero pad rows 49..63 of BOTH x buffers + overlapped DMA ----
  if (tid < 240){
    int rr = 49 + (tid >> 4), ck = tid & 15;
    short8 z = {};
    *(short8*)(lds + rr * 128 + ck * 8) = z;
    *(short8*)(lds + 8192 + rr * 128 + ck * 8) = z;
  }
#pragma unroll
  for (int it = 0; it < 4; ++it){
    int chunk = it * 256 + tid;              // x half0 -> [0,8192)
    if (chunk < 784) GLL16(xwin + chunk * 8, lds + chunk * 8);
  }
#pragma unroll
  for (int it = 0; it < 4; ++it){
    int chunk = it * 256 + tid;              // x half1 -> [8192,16384), stays in flight
    if (chunk < 784) GLL16(xwin + 8192 + chunk * 8, lds + 8192 + chunk * 8);
  }
  if (hl == 0) asm volatile("s_waitcnt vmcnt(4) lgkmcnt(0)" ::: "memory");  // wave0: 4 x1 ops remain
  else         asm volatile("s_waitcnt vmcnt(3) lgkmcnt(0)" ::: "memory");  // waves1-3: 3 remain
  __builtin_amdgcn_s_barrier();              // x0 (and zero-fill) visible to all waves

  // ---- phase 1: qkv GEMM; q,k transposed (D[ch][px]); v natural (D[px][ch]) ----
  f32x4 aqT[2][4] = {}, akT[2][4] = {}, avN[4][2] = {};
  for (int half = 0; half < 2; ++half){
    const unsigned short* xb = lds + half * 8192;
    for (int kq = 0; kq < 4; ++kq){
      short8 xf[4];
#pragma unroll
      for (int pt = 0; pt < 4; ++pt){
        int px = pt * 16 + (lane & 15);
        int c = kq * 4 + (lane >> 4);        // chunk 0..15
        int cs = (c & 8) | ((c ^ px) & 7);
        xf[pt] = *(const short8*)(xb + px * 128 + cs * 8);
      }
      short8 wfr[6];
      int kqg = half * 4 + kq;
#pragma unroll
      for (int t = 0; t < 6; ++t)
        wfr[t] = *(const short8*)(Wf + ((size_t)((hg * 8 + kqg) * 6 + t) * 64 + lane) * 8);
#pragma unroll
      for (int pt = 0; pt < 4; ++pt){
        aqT[0][pt] = MFMA16(wfr[0], xf[pt], aqT[0][pt]);   // D[ch][px]
        aqT[1][pt] = MFMA16(wfr[1], xf[pt], aqT[1][pt]);
        akT[0][pt] = MFMA16(wfr[2], xf[pt], akT[0][pt]);
        akT[1][pt] = MFMA16(wfr[3], xf[pt], akT[1][pt]);
        avN[pt][0] = MFMA16(xf[pt], wfr[4], avN[pt][0]);   // D[px][ch]
        avN[pt][1] = MFMA16(xf[pt], wfr[5], avN[pt][1]);
      }
    }
    if (half == 0){
      asm volatile("s_waitcnt vmcnt(0)" ::: "memory");  // own x1 DMAs landed
      __builtin_amdgcn_s_barrier();                     // all waves' x1 landed
    }
  }
  __syncthreads();                           // all x reads done -> x0/x1 become vT/q

  // write q,k -> [px][128ch swz], b64-packed (lane rows = 4 consecutive ch)
#pragma unroll
  for (int t = 0; t < 2; ++t)
#pragma unroll
    for (int pt = 0; pt < 4; ++pt){
      int px = pt * 16 + (lane & 15);
      int ck = hl * 4 + t * 2 + ((lane >> 4) >> 1);     // chl>>3, const over j
      int sub = ((lane >> 4) & 1) * 4;                  // chl&7 base
      int pos = px * 128 + (((ck & 8) | ((ck ^ px) & 7)) << 3) + sub;
      *(unsigned long long*)(lds + 8192 + pos)  = pack4(aqT[t][pt]);   // over x1
      *(unsigned long long*)(lds + 16384 + pos) = pack4(akT[t][pt]);
    }
  // write vT -> x0 region [128ch][64px swz], b64-packed (lane rows = 4 consecutive px)
#pragma unroll
  for (int ct = 0; ct < 2; ++ct)
#pragma unroll
    for (int pt = 0; pt < 4; ++pt){
      int chl = hl * 32 + ct * 16 + (lane & 15);
      int pxb = pt * 16 + ((lane >> 4) << 2);
      int addr = chl * 64 + (((pxb >> 3) ^ (chl & 7)) << 3) + (pxb & 7);
      *(unsigned long long*)(lds + addr) = pack4(avN[pt][ct]);
    }

  // ---- phase 2: S^T = K * Q^T (own head's q,k -- written by THIS wave, in-order LDS) ----
  short8 kf[4], qf[4];
#pragma unroll
  for (int i = 0; i < 4; ++i){
    int px = i * 16 + (lane & 15);
    int c = hl * 4 + (lane >> 4);            // own head's chunks
    int cs = (c & 8) | ((c ^ px) & 7);
    qf[i] = *(const short8*)(lds + 8192 + px * 128 + cs * 8);
    kf[i] = *(const short8*)(lds + 16384 + px * 128 + cs * 8);
  }
  f32x4 s[4][4] = {};
#pragma unroll
  for (int mi = 0; mi < 4; ++mi)
#pragma unroll
    for (int ni = 0; ni < 4; ++ni)
      s[mi][ni] = MFMA16(kf[mi], qf[ni], s[mi][ni]);
  __syncthreads();                           // all q/k reads + vT writes visible; q+k -> sP

  // ---- softmax over k' per q column; P b64-packed to own sP ----
  const float cexp = 0.25504437f;            // log2(e)/sqrt(32)
  unsigned short* sP = lds + 8192 + hl * 4096;
  bool q0 = (lane < 16);
#pragma unroll
  for (int ni = 0; ni < 4; ++ni){
    float m = s[0][ni][0];
#pragma unroll
    for (int mi = 0; mi < 3; ++mi)
#pragma unroll
      for (int r = 0; r < 4; ++r)
        if (mi | r) m = fmaxf(m, s[mi][ni][r]);
    m = fmaxf(m, q0 ? s[3][ni][0] : -3.0e38f);
    m = fmaxf(m, __shfl_xor(m, 16));
    m = fmaxf(m, __shfl_xor(m, 32));
    float sum = 0.f;
    float pv[4][4];
#pragma unroll
    for (int mi = 0; mi < 3; ++mi)
#pragma unroll
      for (int r = 0; r < 4; ++r){
        float e2 = exp2f((s[mi][ni][r] - m) * cexp);
        pv[mi][r] = e2; sum += e2;
      }
    {
      float e2 = q0 ? exp2f((s[3][ni][0] - m) * cexp) : 0.f;
      pv[3][0] = e2; sum += e2;
      pv[3][1] = 0.f; pv[3][2] = 0.f; pv[3][3] = 0.f;
    }
    sum += __shfl_xor(sum, 16);
    sum += __shfl_xor(sum, 32);
    float inv = 1.0f / sum;
    int q = ni * 16 + (lane & 15);
#pragma unroll
    for (int mi = 0; mi < 4; ++mi){
      int kpb2 = mi * 32 + ((lane >> 4) << 3);          // byte offset of 4-kp group
      int bo = (q * 128 + kpb2) ^ ((q & 7) << 4);
      unsigned long long pk =
          (unsigned long long)f2bf(pv[mi][0] * inv)
        | ((unsigned long long)f2bf(pv[mi][1] * inv) << 16)
        | ((unsigned long long)f2bf(pv[mi][2] * inv) << 32)
        | ((unsigned long long)f2bf(pv[mi][3] * inv) << 48);
      *(unsigned long long*)((char*)sP + bo) = pk;
    }
  }

  // ---- phase 3: O^T = V^T * P^T (own sP + own vT rows); D[ch][q] ----
  f32x4 oT[2][4] = {};
#pragma unroll
  for (int kc = 0; kc < 2; ++kc){
    short8 pa[4], vb[2];
#pragma unroll
    for (int mtp = 0; mtp < 4; ++mtp){
      int row = mtp * 16 + (lane & 15);
      int bo = (row * 128 + kc * 64 + (lane >> 4) * 16) ^ ((row & 7) << 4);
      pa[mtp] = *(const short8*)((char*)sP + bo);
    }
#pragma unroll
    for (int ntp = 0; ntp < 2; ++ntp){
      int chl = hl * 32 + ntp * 16 + (lane & 15);
      int k0 = kc * 32 + (lane >> 4) * 8;
      vb[ntp] = *(const short8*)(lds + chl * 64 + (((k0 >> 3) ^ (chl & 7)) << 3));
    }
#pragma unroll
    for (int mtp = 0; mtp < 4; ++mtp)
#pragma unroll
      for (int ntp = 0; ntp < 2; ++ntp)
        oT[ntp][mtp] = MFMA16(vb[ntp], pa[mtp], oT[ntp][mtp]);
  }
  // O -> own sP area [64px(q)][32ch swz], b64-packed (lane rows = 4 consecutive ch)
#pragma unroll
  for (int ntp = 0; ntp < 2; ++ntp)
#pragma unroll
    for (int mtp = 0; mtp < 4; ++mtp){
      int px = mtp * 16 + (lane & 15);
      int chb = ntp * 16 + ((lane >> 4) << 2);
      int c2 = chb >> 3;
      int addr = px * 32 + (((c2 ^ px) & 3) << 3) + (chb & 7);
      *(unsigned long long*)(sP + addr) = pack4(oT[ntp][mtp]);
    }
  __syncthreads();

  // ---- phase 4: cooperative 16B panel stores (this block's 4 heads) ----
  size_t pb0 = (size_t)b * 392 * 4;
#pragma unroll
  for (int it = 0; it < 4; ++it){
    int id = it * 256 + tid;                 // 0..1023 = 64px * 16 chunks
    int px = id >> 4, ck = id & 15;
    if (px < 49){
      int hl2 = ck >> 2, c2 = ck & 3;
      short8 v = *(const short8*)(lds + 8192 + hl2 * 4096 + px * 32 + (((c2 ^ px) & 3) << 3));
      int ch0 = (hh * 4 + hl2) * 32 + c2 * 8;
      int pg = (wh * 7 + px / 7) * 224 + ww * 7 + px % 7;
      int nt = pg >> 7, pr = pg & 127;
      size_t off = (pb0 + (size_t)nt * 4 + (ch0 >> 6)) * 8192 + panel_off(pr, ch0 & 63);
      *(short8*)(attnP + off) = v;
    }
  }
}

// ---------------- GEMM out + residual (bf16 y) + per-block BN partials ----------------
// counted-vmcnt 2-deep pipeline: next tile's 8 loads stay in flight across barriers
__global__ __launch_bounds__(256) void k_gemm_out(const unsigned short* __restrict__ Wp,
                                                  const unsigned short* __restrict__ Bp,
                                                  const float* __restrict__ x,
                                                  unsigned short* __restrict__ ybf,
                                                  float* __restrict__ partials){
  int bid = blockIdx.x;
  int wg = (bid & 7) * 392 + (bid >> 3);     // 3136 = 8*392
  int mt = wg & 1; int rest = wg >> 1;       // mt fastest
  int nt = rest % 392; int b = rest / 392;

  __shared__ __align__(16) unsigned short lds[32768];  // dbuf (2 x 32KB)

  int tid = threadIdx.x;
  int lane = tid & 63;
  int wave = tid >> 6;
  int wm = wave >> 1, wn = wave & 1;

  const unsigned short* Apan = Wp + (size_t)mt * 4 * 8192;
  const unsigned short* Bpan = Bp + ((size_t)(b * 392 + nt)) * 4 * 8192;

  int aoff[2][4], boff[2][4];
#pragma unroll
  for (int kk = 0; kk < 2; ++kk)
#pragma unroll
    for (int i = 0; i < 4; ++i){
      int rowA = wm * 64 + i * 16 + (lane & 15);
      aoff[kk][i] = rowA * 64 + (((kk * 4 + (lane >> 4)) ^ (rowA & 7)) << 3);
      int rowB = wn * 64 + i * 16 + (lane & 15);
      boff[kk][i] = rowB * 64 + (((kk * 4 + (lane >> 4)) ^ (rowB & 7)) << 3);
    }
  int cb = wave * 2048;
  f32x4 acc[4][4] = {};

  // prologue: T0 -> buf0, T1 -> buf1 (16 loads in flight per wave)
#pragma unroll
  for (int j = 0; j < 4; ++j){
    int o2 = cb + j * 512;
    GLL16(Apan + o2 + lane * 8, lds + o2);
    GLL16(Bpan + o2 + lane * 8, lds + 8192 + o2);
  }
#pragma unroll
  for (int j = 0; j < 4; ++j){
    int o2 = cb + j * 512;
    GLL16(Apan + 8192 + o2 + lane * 8, lds + 16384 + o2);
    GLL16(Bpan + 8192 + o2 + lane * 8, lds + 24576 + o2);
  }

  int cur = 0;
  for (int kq = 0; kq < 4; ++kq){
    if (kq < 3) asm volatile("s_waitcnt vmcnt(8)" ::: "memory");  // tile kq landed; next stays in flight
    else        asm volatile("s_waitcnt vmcnt(0)" ::: "memory");
    __builtin_amdgcn_s_barrier();
    const unsigned short* Alds = lds + cur * 16384;
    const unsigned short* Blds = Alds + 8192;
#pragma unroll
    for (int kk = 0; kk < 2; ++kk){
      short8 af[4], bfv[4];
#pragma unroll
      for (int i = 0; i < 4; ++i) af[i]  = *(const short8*)(Alds + aoff[kk][i]);
#pragma unroll
      for (int j = 0; j < 4; ++j) bfv[j] = *(const short8*)(Blds + boff[kk][j]);
#pragma unroll
      for (int i = 0; i < 4; ++i)
#pragma unroll
        for (int j = 0; j < 4; ++j)
          acc[i][j] = MFMA16(af[i], bfv[j], acc[i][j]);
    }
    asm volatile("s_waitcnt lgkmcnt(0)" ::: "memory");   // this wave's LDS reads consumed
    __builtin_amdgcn_s_barrier();                        // all waves done reading buf[cur]
    if (kq < 2){
      const unsigned short* Ak = Apan + (kq + 2) * 8192;
      const unsigned short* Bk = Bpan + (kq + 2) * 8192;
      unsigned short* dst = lds + cur * 16384;
#pragma unroll
      for (int j = 0; j < 4; ++j){
        int o2 = cb + j * 512;
        GLL16(Ak + o2 + lane * 8, dst + o2);
        GLL16(Bk + o2 + lane * 8, dst + 8192 + o2);
      }
    }
    cur ^= 1;
  }
  // epilogue: residual add, bf16 y store, per-channel partial sums
  float ps[4][4] = {}, pq[4][4] = {};
#pragma unroll
  for (int i = 0; i < 4; ++i)
#pragma unroll
    for (int j = 0; j < 4; ++j){
      int o = mt * 128 + wm * 64 + i * 16 + (lane >> 4) * 4;
      int p = nt * 128 + wn * 64 + j * 16 + (lane & 15);
      size_t base = ((size_t)(b * 256 + o)) * HW_ + p;
#pragma unroll
      for (int r2 = 0; r2 < 4; ++r2){
        float v = acc[i][j][r2] + x[base + (size_t)r2 * HW_];
        ybf[base + (size_t)r2 * HW_] = f2bf(v);
        ps[i][r2] += v;
        pq[i][r2] += v * v;
      }
    }
  float* fl = (float*)lds;    // [wn 2][cl 128] sums, +256 sq
#pragma unroll
  for (int i = 0; i < 4; ++i)
#pragma unroll
    for (int r2 = 0; r2 < 4; ++r2){
      float a = ps[i][r2], q2 = pq[i][r2];
      a += __shfl_xor(a, 1);  q2 += __shfl_xor(q2, 1);
      a += __shfl_xor(a, 2);  q2 += __shfl_xor(q2, 2);
      a += __shfl_xor(a, 4);  q2 += __shfl_xor(q2, 4);
      a += __shfl_xor(a, 8);  q2 += __shfl_xor(q2, 8);
      if ((lane & 15) == 0){
        int cl = wm * 64 + i * 16 + (lane >> 4) * 4 + r2;
        fl[wn * 128 + cl] = a;
        fl[256 + wn * 128 + cl] = q2;
      }
    }
  __syncthreads();
  if (tid < 128){
    partials[(size_t)wg * 256 + tid]       = fl[tid] + fl[128 + tid];
    partials[(size_t)wg * 256 + 128 + tid] = fl[256 + tid] + fl[384 + tid];
  }
}

// ---------------- reduce per-block partials -> mean / rsqrt ----------------
__global__ __launch_bounds__(256) void k_stats2(const float* __restrict__ partials, float* __restrict__ stats){
  int c = blockIdx.x;           // 0..255
  int mt = c >> 7, cl = c & 127;
  int t = threadIdx.x;
  float s = 0.f, q = 0.f;
  for (int idx = t; idx < 1568; idx += 256){
    const float* p = partials + (size_t)(2 * idx + mt) * 256;
    s += p[cl]; q += p[128 + cl];
  }
  __shared__ float r1[256], r2[256];
  r1[t] = s; r2[t] = q; __syncthreads();
  for (int off = 128; off > 0; off >>= 1){
    if (t < off){ r1[t] += r1[t + off]; r2[t] += r2[t + off]; }
    __syncthreads();
  }
  if (t == 0){
    float mean = r1[0] * (1.f / 200704.f);
    float var  = r2[0] * (1.f / 200704.f) - mean * mean;
    stats[c] = mean;
    stats[256 + c] = rsqrtf(var + 1e-5f);
  }
}

// ---------------- normalize: bf16 y -> fp32 out (int32 indexing) ----------------
__global__ __launch_bounds__(256) void k_norm(const unsigned short* __restrict__ ybf,
                                              const float* __restrict__ stats,
                                              const float* __restrict__ gamma, const float* __restrict__ beta,
                                              float* __restrict__ out){
  const int total = 6422528;   // 51380224 / 8
  for (int idx = blockIdx.x * 256 + threadIdx.x; idx < total; idx += gridDim.x * 256){
    int c = (idx / 6272) & 255;  // 6272 = 50176/8 ; 32-bit magic div
    float sc = stats[256 + c] * gamma[c];
    float sh = beta[c] - stats[c] * sc;
    short8 v = *(const short8*)(ybf + (size_t)idx * 8);
    float4 o0, o1;
    o0.x = bf2f((unsigned short)v[0]) * sc + sh;
    o0.y = bf2f((unsigned short)v[1]) * sc + sh;
    o0.z = bf2f((unsigned short)v[2]) * sc + sh;
    o0.w = bf2f((unsigned short)v[3]) * sc + sh;
    o1.x = bf2f((unsigned short)v[4]) * sc + sh;
    o1.y = bf2f((unsigned short)v[5]) * sc + sh;
    o1.z = bf2f((unsigned short)v[6]) * sc + sh;
    o1.w = bf2f((unsigned short)v[7]) * sc + sh;
    *(float4*)(out + (size_t)idx * 8)     = o0;
    *(float4*)(out + (size_t)idx * 8 + 4) = o1;
  }
}

extern "C" void kernel_launch(void* const* d_in, const int* in_sizes, int n_in,
                              void* d_out, int out_size, void* d_ws, size_t ws_size,
                              hipStream_t stream){
  const float* x     = (const float*)d_in[0];
  const float* Wq    = (const float*)d_in[1];
  const float* Wk    = (const float*)d_in[2];
  const float* Wv    = (const float*)d_in[3];
  const float* Wo    = (const float*)d_in[4];
  const float* gamma = (const float*)d_in[5];
  const float* beta  = (const float*)d_in[6];
  float* out = (float*)d_out;

  char* ws = (char*)d_ws;
  unsigned short* Wf     = (unsigned short*)ws;                               // 393216 B
  unsigned short* Wo_b   = (unsigned short*)(ws + 393216);                    // 131072 B
  float*          stats  = (float*)(ws + 524288);                             // 2048 B
  unsigned short* xw     = (unsigned short*)(ws + 1048576);                   // 134217728 B
  unsigned short* attnP  = (unsigned short*)(ws + 1048576 + 134217728);       // 102760448 B
  float*          partials = (float*)(ws + 1048576 + 134217728 + 102760448);  // 3211264 B
  unsigned short* ybf    = xw;   // alias: xw dead after k_fused (stream-ordered)

  k_convw<<<128, 256, 0, stream>>>(Wq, Wk, Wv, Wo, Wf, Wo_b);
  k_xw<<<2048, 256, 0, stream>>>(x, xw);
  k_fused<<<8192, 256, 0, stream>>>(xw, Wf, attnP);
  k_gemm_out<<<3136, 256, 0, stream>>>(Wo_b, attnP, x, ybf, partials);
  k_stats2<<<256, 256, 0, stream>>>(partials, stats);
  k_norm<<<4096, 256, 0, stream>>>(ybf, stats, gamma, beta, out);
}

// Round 17
// 432.862 us; speedup vs baseline: 1.1027x; 1.0329x over previous
//
#include <hip/hip_runtime.h>
#include <stdint.h>

typedef __attribute__((ext_vector_type(8))) short short8;
typedef __attribute__((ext_vector_type(4))) float f32x4;

#define MFMA16(a,b,c) __builtin_amdgcn_mfma_f32_16x16x32_bf16((a),(b),(c),0,0,0)

// async global->LDS DMA, 16B per lane; LDS dest = wave-uniform base + lane*16B
#define GLL16(g, l) __builtin_amdgcn_global_load_lds( \
    (const __attribute__((address_space(1))) void*)(g), \
    (__attribute__((address_space(3))) void*)(l), 16, 0, 0)

__device__ __forceinline__ unsigned short f2bf(float f){
  unsigned u = __builtin_bit_cast(unsigned, f);
  u += 0x7fffu + ((u >> 16) & 1u);
  return (unsigned short)(u >> 16);
}
__device__ __forceinline__ float bf2f(unsigned short s){
  unsigned u = ((unsigned)s) << 16;
  return __builtin_bit_cast(float, u);
}
// pack 4 f32 -> 4 bf16 in a u64 (RNE, proven f2bf path)
__device__ __forceinline__ unsigned long long pack4(f32x4 v){
  return (unsigned long long)f2bf(v[0])
       | ((unsigned long long)f2bf(v[1]) << 16)
       | ((unsigned long long)f2bf(v[2]) << 32)
       | ((unsigned long long)f2bf(v[3]) << 48);
}

static constexpr int HW_ = 50176;   // 224*224

// offset of element (row r 0..127, k c64 0..63) inside one 8192-elem panel,
// XOR-swizzled so ds_read_b128 of a 16-lane column slice is conflict-free
__device__ __forceinline__ int panel_off(int r, int c64){
  return r * 64 + ((((c64 >> 3) ^ (r & 7))) << 3) + (c64 & 7);
}

// ---------------- weights fp32 -> bf16 ----------------
__global__ __launch_bounds__(256) void k_convw(const float* __restrict__ Wq, const float* __restrict__ Wk,
                        const float* __restrict__ Wv, const float* __restrict__ Wo,
                        unsigned short* __restrict__ Wf, unsigned short* __restrict__ Wob){
  int gid = blockIdx.x * 256 + threadIdx.x;   // grid 128 -> 32768
  if (gid < 24576){
    int lane = gid & 63;
    int r1 = gid >> 6;          // 0..383
    int t = r1 % 6;
    int r2 = r1 / 6;            // 0..63
    int kq = r2 & 7, hh = r2 >> 3;
    const float* W = (t < 2) ? Wq : (t < 4) ? Wk : Wv;
    int ch = hh * 32 + (t & 1) * 16 + (lane & 15);
    int k0 = kq * 32 + (lane >> 4) * 8;
    const float* src = W + ch * 256 + k0;
    float4 a = *(const float4*)src, b2 = *(const float4*)(src + 4);
    short8 v;
    v[0]=f2bf(a.x); v[1]=f2bf(a.y); v[2]=f2bf(a.z); v[3]=f2bf(a.w);
    v[4]=f2bf(b2.x); v[5]=f2bf(b2.y); v[6]=f2bf(b2.z); v[7]=f2bf(b2.w);
    *(short8*)(Wf + (size_t)gid * 8) = v;
  } else {
    int og = gid - 24576;       // 0..8191
    int o = og >> 5, ck = og & 31;
    const float* src = Wo + o * 256 + ck * 8;
    float4 a = *(const float4*)src, b2 = *(const float4*)(src + 4);
    short8 v;
    v[0]=f2bf(a.x); v[1]=f2bf(a.y); v[2]=f2bf(a.z); v[3]=f2bf(a.w);
    v[4]=f2bf(b2.x); v[5]=f2bf(b2.y); v[6]=f2bf(b2.z); v[7]=f2bf(b2.w);
    int kq = ck >> 3;
    int off = panel_off(o & 127, (ck & 7) * 8);
    *(short8*)(Wob + ((o >> 7) * 4 + kq) * 8192 + off) = v;
  }
}

// ---------------- x (B,C,H,W) f32 -> xw[win][half 2][px 49/64][128c swz] bf16 ----------------
__global__ __launch_bounds__(256) void k_xw(const float* __restrict__ x, unsigned short* __restrict__ xw){
  int bid = blockIdx.x;
  int cq = bid & 15, wh = (bid >> 4) & 31, b = bid >> 9;
  __shared__ __align__(16) unsigned short tile[25088];  // 49 KB
  int tid = threadIdx.x;
  for (int it = 0; it < 25; ++it){
    int idx = it * 256 + tid;
    if (idx < 6272){
      int c = idx & 15;
      int t2 = idx >> 4;                  // 0..391
      int r = t2 / 56;
      int w4 = t2 % 56;
      float4 v = *(const float4*)(x + ((size_t)(b * 256 + cq * 16 + c)) * HW_ + (wh * 7 + r) * 224 + w4 * 4);
      float vv[4] = {v.x, v.y, v.z, v.w};
      int w0 = w4 * 4;
      int ww = w0 / 7;
      int cl = w0 % 7;
#pragma unroll
      for (int i = 0; i < 4; ++i){
        int px = r * 7 + cl;
        tile[ww * 784 + px * 16 + (((c >> 3) ^ (px & 1)) << 3) + (c & 7)] = f2bf(vv[i]);
        if (++cl == 7){ cl = 0; ++ww; }
      }
    }
  }
  __syncthreads();
  size_t wb = ((size_t)(b * 1024 + wh * 32)) * 16384;
  for (int it = 0; it < 13; ++it){
    int id = it * 256 + tid;
    if (id < 3136){                       // 32 ww x 49 px x 2 chunk-slots
      int ww = id / 98;
      int rem = id - ww * 98;
      int px = rem >> 1, hb = rem & 1;
      short8 v = *(const short8*)(tile + ww * 784 + px * 16 + ((hb ^ (px & 1)) << 3));
      int cc = cq * 2 + hb;               // global 8-ch chunk 0..31
      int half = cc >> 4, c4 = cc & 15;
      int pos = (c4 & 8) | ((c4 ^ px) & 7);
      *(short8*)(xw + wb + (size_t)ww * 16384 + half * 8192 + px * 128 + pos * 8) = v;
    }
  }
}

// ---------------- fused: qkv GEMM + window attention ----------------
// block = (window, 4-head half), 4 waves = 4 heads, 48 KB LDS -> 3 blocks/CU
// x0 at [0,8192), x1 at [8192,16384) (overlapped DMA, counted vmcnt);
// q overwrites x1, vT overwrites x0 after a single post-phase-1 barrier.
__global__ __launch_bounds__(256, 3) void k_fused(const unsigned short* __restrict__ xw,
                                                  const unsigned short* __restrict__ Wf,
                                                  unsigned short* __restrict__ attnP){
  int bid = blockIdx.x;
  int wg = (bid & 7) * 1024 + (bid >> 3);   // 8192 = 8*1024; window pair on same XCD
  int hh = wg & 1; int win = wg >> 1;
  int b = win >> 10;
  int wh = (win >> 5) & 31, ww = win & 31;
  int tid = threadIdx.x;
  int lane = tid & 63;
  int hl = tid >> 6;                         // local head 0..3
  int hg = hh * 4 + hl;                      // global head

  __shared__ __align__(16) unsigned short lds[24576];   // 48 KB

  const unsigned short* xwin = xw + (size_t)win * 16384;

  // ---- phase 0: zero pad rows 49..63 of BOTH x buffers + overlapped DMA ----
  if (tid < 240){
    int rr = 49 + (tid >> 4), ck = tid & 15;
    short8 z = {};
    *(short8*)(lds + rr * 128 + ck * 8) = z;
    *(short8*)(lds + 8192 + rr * 128 + ck * 8) = z;
  }
#pragma unroll
  for (int it = 0; it < 4; ++it){
    int chunk = it * 256 + tid;              // x half0 -> [0,8192)
    if (chunk < 784) GLL16(xwin + chunk * 8, lds + chunk * 8);
  }
#pragma unroll
  for (int it = 0; it < 4; ++it){
    int chunk = it * 256 + tid;              // x half1 -> [8192,16384), stays in flight
    if (chunk < 784) GLL16(xwin + 8192 + chunk * 8, lds + 8192 + chunk * 8);
  }
  if (hl == 0) asm volatile("s_waitcnt vmcnt(4) lgkmcnt(0)" ::: "memory");  // wave0: 4 x1 ops remain
  else         asm volatile("s_waitcnt vmcnt(3) lgkmcnt(0)" ::: "memory");  // waves1-3: 3 remain
  __builtin_amdgcn_s_barrier();              // x0 (and zero-fill) visible to all waves

  // ---- phase 1: qkv GEMM; q,k transposed (D[ch][px]); v natural (D[px][ch]) ----
  f32x4 aqT[2][4] = {}, akT[2][4] = {}, avN[4][2] = {};
  for (int half = 0; half < 2; ++half){
    const unsigned short* xb = lds + half * 8192;
    for (int kq = 0; kq < 4; ++kq){
      short8 xf[4];
#pragma unroll
      for (int pt = 0; pt < 4; ++pt){
        int px = pt * 16 + (lane & 15);
        int c = kq * 4 + (lane >> 4);        // chunk 0..15
        int cs = (c & 8) | ((c ^ px) & 7);
        xf[pt] = *(const short8*)(xb + px * 128 + cs * 8);
      }
      short8 wfr[6];
      int kqg = half * 4 + kq;
#pragma unroll
      for (int t = 0; t < 6; ++t)
        wfr[t] = *(const short8*)(Wf + ((size_t)((hg * 8 + kqg) * 6 + t) * 64 + lane) * 8);
#pragma unroll
      for (int pt = 0; pt < 4; ++pt){
        aqT[0][pt] = MFMA16(wfr[0], xf[pt], aqT[0][pt]);   // D[ch][px]
        aqT[1][pt] = MFMA16(wfr[1], xf[pt], aqT[1][pt]);
        akT[0][pt] = MFMA16(wfr[2], xf[pt], akT[0][pt]);
        akT[1][pt] = MFMA16(wfr[3], xf[pt], akT[1][pt]);
        avN[pt][0] = MFMA16(xf[pt], wfr[4], avN[pt][0]);   // D[px][ch]
        avN[pt][1] = MFMA16(xf[pt], wfr[5], avN[pt][1]);
      }
    }
    if (half == 0){
      asm volatile("s_waitcnt vmcnt(0)" ::: "memory");  // own x1 DMAs landed
      __builtin_amdgcn_s_barrier();                     // all waves' x1 landed
    }
  }
  __syncthreads();                           // all x reads done -> x0/x1 become vT/q

  // write q,k -> [px][128ch swz], b64-packed (lane rows = 4 consecutive ch)
#pragma unroll
  for (int t = 0; t < 2; ++t)
#pragma unroll
    for (int pt = 0; pt < 4; ++pt){
      int px = pt * 16 + (lane & 15);
      int ck = hl * 4 + t * 2 + ((lane >> 4) >> 1);     // chl>>3, const over j
      int sub = ((lane >> 4) & 1) * 4;                  // chl&7 base
      int pos = px * 128 + (((ck & 8) | ((ck ^ px) & 7)) << 3) + sub;
      *(unsigned long long*)(lds + 8192 + pos)  = pack4(aqT[t][pt]);   // over x1
      *(unsigned long long*)(lds + 16384 + pos) = pack4(akT[t][pt]);
    }
  // write vT -> x0 region [128ch][64px swz], b64-packed (lane rows = 4 consecutive px)
#pragma unroll
  for (int ct = 0; ct < 2; ++ct)
#pragma unroll
    for (int pt = 0; pt < 4; ++pt){
      int chl = hl * 32 + ct * 16 + (lane & 15);
      int pxb = pt * 16 + ((lane >> 4) << 2);
      int addr = chl * 64 + (((pxb >> 3) ^ (chl & 7)) << 3) + (pxb & 7);
      *(unsigned long long*)(lds + addr) = pack4(avN[pt][ct]);
    }

  // ---- phase 2: S^T = K * Q^T (own head's q,k -- written by THIS wave, in-order LDS) ----
  short8 kf[4], qf[4];
#pragma unroll
  for (int i = 0; i < 4; ++i){
    int px = i * 16 + (lane & 15);
    int c = hl * 4 + (lane >> 4);            // own head's chunks
    int cs = (c & 8) | ((c ^ px) & 7);
    qf[i] = *(const short8*)(lds + 8192 + px * 128 + cs * 8);
    kf[i] = *(const short8*)(lds + 16384 + px * 128 + cs * 8);
  }
  f32x4 s[4][4] = {};
#pragma unroll
  for (int mi = 0; mi < 4; ++mi)
#pragma unroll
    for (int ni = 0; ni < 4; ++ni)
      s[mi][ni] = MFMA16(kf[mi], qf[ni], s[mi][ni]);
  __syncthreads();                           // all q/k reads + vT writes visible; q+k -> sP

  // ---- softmax over k' per q column; P b64-packed to own sP ----
  const float cexp = 0.25504437f;            // log2(e)/sqrt(32)
  unsigned short* sP = lds + 8192 + hl * 4096;
  bool q0 = (lane < 16);
#pragma unroll
  for (int ni = 0; ni < 4; ++ni){
    float m = s[0][ni][0];
#pragma unroll
    for (int mi = 0; mi < 3; ++mi)
#pragma unroll
      for (int r = 0; r < 4; ++r)
        if (mi | r) m = fmaxf(m, s[mi][ni][r]);
    m = fmaxf(m, q0 ? s[3][ni][0] : -3.0e38f);
    m = fmaxf(m, __shfl_xor(m, 16));
    m = fmaxf(m, __shfl_xor(m, 32));
    float sum = 0.f;
    float pv[4][4];
#pragma unroll
    for (int mi = 0; mi < 3; ++mi)
#pragma unroll
      for (int r = 0; r < 4; ++r){
        float e2 = exp2f((s[mi][ni][r] - m) * cexp);
        pv[mi][r] = e2; sum += e2;
      }
    {
      float e2 = q0 ? exp2f((s[3][ni][0] - m) * cexp) : 0.f;
      pv[3][0] = e2; sum += e2;
      pv[3][1] = 0.f; pv[3][2] = 0.f; pv[3][3] = 0.f;
    }
    sum += __shfl_xor(sum, 16);
    sum += __shfl_xor(sum, 32);
    float inv = 1.0f / sum;
    int q = ni * 16 + (lane & 15);
#pragma unroll
    for (int mi = 0; mi < 4; ++mi){
      int kpb2 = mi * 32 + ((lane >> 4) << 3);          // byte offset of 4-kp group
      int bo = (q * 128 + kpb2) ^ ((q & 7) << 4);
      unsigned long long pk =
          (unsigned long long)f2bf(pv[mi][0] * inv)
        | ((unsigned long long)f2bf(pv[mi][1] * inv) << 16)
        | ((unsigned long long)f2bf(pv[mi][2] * inv) << 32)
        | ((unsigned long long)f2bf(pv[mi][3] * inv) << 48);
      *(unsigned long long*)((char*)sP + bo) = pk;
    }
  }

  // ---- phase 3: O^T = V^T * P^T (own sP + own vT rows); D[ch][q] ----
  f32x4 oT[2][4] = {};
#pragma unroll
  for (int kc = 0; kc < 2; ++kc){
    short8 pa[4], vb[2];
#pragma unroll
    for (int mtp = 0; mtp < 4; ++mtp){
      int row = mtp * 16 + (lane & 15);
      int bo = (row * 128 + kc * 64 + (lane >> 4) * 16) ^ ((row & 7) << 4);
      pa[mtp] = *(const short8*)((char*)sP + bo);
    }
#pragma unroll
    for (int ntp = 0; ntp < 2; ++ntp){
      int chl = hl * 32 + ntp * 16 + (lane & 15);
      int k0 = kc * 32 + (lane >> 4) * 8;
      vb[ntp] = *(const short8*)(lds + chl * 64 + (((k0 >> 3) ^ (chl & 7)) << 3));
    }
#pragma unroll
    for (int mtp = 0; mtp < 4; ++mtp)
#pragma unroll
      for (int ntp = 0; ntp < 2; ++ntp)
        oT[ntp][mtp] = MFMA16(vb[ntp], pa[mtp], oT[ntp][mtp]);
  }
  // O -> own sP area [64px(q)][32ch swz], b64-packed (lane rows = 4 consecutive ch)
#pragma unroll
  for (int ntp = 0; ntp < 2; ++ntp)
#pragma unroll
    for (int mtp = 0; mtp < 4; ++mtp){
      int px = mtp * 16 + (lane & 15);
      int chb = ntp * 16 + ((lane >> 4) << 2);
      int c2 = chb >> 3;
      int addr = px * 32 + (((c2 ^ px) & 3) << 3) + (chb & 7);
      *(unsigned long long*)(sP + addr) = pack4(oT[ntp][mtp]);
    }
  __syncthreads();

  // ---- phase 4: cooperative 16B panel stores (this block's 4 heads) ----
  size_t pb0 = (size_t)b * 392 * 4;
#pragma unroll
  for (int it = 0; it < 4; ++it){
    int id = it * 256 + tid;                 // 0..1023 = 64px * 16 chunks
    int px = id >> 4, ck = id & 15;
    if (px < 49){
      int hl2 = ck >> 2, c2 = ck & 3;
      short8 v = *(const short8*)(lds + 8192 + hl2 * 4096 + px * 32 + (((c2 ^ px) & 3) << 3));
      int ch0 = (hh * 4 + hl2) * 32 + c2 * 8;
      int pg = (wh * 7 + px / 7) * 224 + ww * 7 + px % 7;
      int nt = pg >> 7, pr = pg & 127;
      size_t off = (pb0 + (size_t)nt * 4 + (ch0 >> 6)) * 8192 + panel_off(pr, ch0 & 63);
      *(short8*)(attnP + off) = v;
    }
  }
}

// ---------------- GEMM out + residual (bf16 y) + per-block BN partials ----------------
// counted-vmcnt 2-deep pipeline; epilogue restaged via LDS for full-sector ybf stores
__global__ __launch_bounds__(256) void k_gemm_out(const unsigned short* __restrict__ Wp,
                                                  const unsigned short* __restrict__ Bp,
                                                  const float* __restrict__ x,
                                                  unsigned short* __restrict__ ybf,
                                                  float* __restrict__ partials){
  int bid = blockIdx.x;
  int wg = (bid & 7) * 392 + (bid >> 3);     // 3136 = 8*392
  int mt = wg & 1; int rest = wg >> 1;       // mt fastest
  int nt = rest % 392; int b = rest / 392;

  __shared__ __align__(16) unsigned short lds[32768];  // dbuf (2 x 32KB); epilogue: [128 o][136] tile

  int tid = threadIdx.x;
  int lane = tid & 63;
  int wave = tid >> 6;
  int wm = wave >> 1, wn = wave & 1;

  const unsigned short* Apan = Wp + (size_t)mt * 4 * 8192;
  const unsigned short* Bpan = Bp + ((size_t)(b * 392 + nt)) * 4 * 8192;

  int aoff[2][4], boff[2][4];
#pragma unroll
  for (int kk = 0; kk < 2; ++kk)
#pragma unroll
    for (int i = 0; i < 4; ++i){
      int rowA = wm * 64 + i * 16 + (lane & 15);
      aoff[kk][i] = rowA * 64 + (((kk * 4 + (lane >> 4)) ^ (rowA & 7)) << 3);
      int rowB = wn * 64 + i * 16 + (lane & 15);
      boff[kk][i] = rowB * 64 + (((kk * 4 + (lane >> 4)) ^ (rowB & 7)) << 3);
    }
  int cb = wave * 2048;
  f32x4 acc[4][4] = {};

  // prologue: T0 -> buf0, T1 -> buf1 (16 loads in flight per wave)
#pragma unroll
  for (int j = 0; j < 4; ++j){
    int o2 = cb + j * 512;
    GLL16(Apan + o2 + lane * 8, lds + o2);
    GLL16(Bpan + o2 + lane * 8, lds + 8192 + o2);
  }
#pragma unroll
  for (int j = 0; j < 4; ++j){
    int o2 = cb + j * 512;
    GLL16(Apan + 8192 + o2 + lane * 8, lds + 16384 + o2);
    GLL16(Bpan + 8192 + o2 + lane * 8, lds + 24576 + o2);
  }

  int cur = 0;
  for (int kq = 0; kq < 4; ++kq){
    if (kq < 3) asm volatile("s_waitcnt vmcnt(8)" ::: "memory");  // tile kq landed; next stays in flight
    else        asm volatile("s_waitcnt vmcnt(0)" ::: "memory");
    __builtin_amdgcn_s_barrier();
    const unsigned short* Alds = lds + cur * 16384;
    const unsigned short* Blds = Alds + 8192;
#pragma unroll
    for (int kk = 0; kk < 2; ++kk){
      short8 af[4], bfv[4];
#pragma unroll
      for (int i = 0; i < 4; ++i) af[i]  = *(const short8*)(Alds + aoff[kk][i]);
#pragma unroll
      for (int j = 0; j < 4; ++j) bfv[j] = *(const short8*)(Blds + boff[kk][j]);
#pragma unroll
      for (int i = 0; i < 4; ++i)
#pragma unroll
        for (int j = 0; j < 4; ++j)
          acc[i][j] = MFMA16(af[i], bfv[j], acc[i][j]);
    }
    asm volatile("s_waitcnt lgkmcnt(0)" ::: "memory");   // this wave's LDS reads consumed
    __builtin_amdgcn_s_barrier();                        // all waves done reading buf[cur]
    if (kq < 2){
      const unsigned short* Ak = Apan + (kq + 2) * 8192;
      const unsigned short* Bk = Bpan + (kq + 2) * 8192;
      unsigned short* dst = lds + cur * 16384;
#pragma unroll
      for (int j = 0; j < 4; ++j){
        int o2 = cb + j * 512;
        GLL16(Ak + o2 + lane * 8, dst + o2);
        GLL16(Bk + o2 + lane * 8, dst + 8192 + o2);
      }
    }
    cur ^= 1;
  }
  // epilogue A: residual add -> LDS out-tile [o 128][pitch 136] u16, partials in regs
  unsigned short* lo = lds;                  // staging fully drained by final loop barrier
  float ps[4][4] = {}, pq[4][4] = {};
#pragma unroll
  for (int i = 0; i < 4; ++i)
#pragma unroll
    for (int j = 0; j < 4; ++j){
      int o_loc = wm * 64 + i * 16 + (lane >> 4) * 4;
      int p_loc = wn * 64 + j * 16 + (lane & 15);
      size_t base = ((size_t)(b * 256 + mt * 128 + o_loc)) * HW_ + nt * 128 + p_loc;
#pragma unroll
      for (int r2 = 0; r2 < 4; ++r2){
        float v = acc[i][j][r2] + x[base + (size_t)r2 * HW_];
        lo[(o_loc + r2) * 136 + p_loc] = f2bf(v);
        ps[i][r2] += v;
        pq[i][r2] += v * v;
      }
    }
  __syncthreads();
  // epilogue B: coalesced ybf stores (16 lanes x 16B = full 256B rows)
  {
    size_t orow0 = ((size_t)(b * 256 + mt * 128)) * HW_ + (size_t)nt * 128;
#pragma unroll
    for (int it2 = 0; it2 < 8; ++it2){
      int id = it2 * 256 + tid;              // 0..2047 = 128 o-rows x 16 chunks
      int o_loc = id >> 4, c16 = id & 15;
      short8 v = *(const short8*)(lo + o_loc * 136 + c16 * 8);
      *(short8*)(ybf + orow0 + (size_t)o_loc * HW_ + c16 * 8) = v;
    }
  }
  __syncthreads();                           // all LDS reads done before fl overwrite
  float* fl = (float*)lds;    // [wn 2][cl 128] sums, +256 sq
#pragma unroll
  for (int i = 0; i < 4; ++i)
#pragma unroll
    for (int r2 = 0; r2 < 4; ++r2){
      float a = ps[i][r2], q2 = pq[i][r2];
      a += __shfl_xor(a, 1);  q2 += __shfl_xor(q2, 1);
      a += __shfl_xor(a, 2);  q2 += __shfl_xor(q2, 2);
      a += __shfl_xor(a, 4);  q2 += __shfl_xor(q2, 4);
      a += __shfl_xor(a, 8);  q2 += __shfl_xor(q2, 8);
      if ((lane & 15) == 0){
        int cl = wm * 64 + i * 16 + (lane >> 4) * 4 + r2;
        fl[wn * 128 + cl] = a;
        fl[256 + wn * 128 + cl] = q2;
      }
    }
  __syncthreads();
  if (tid < 128){
    partials[(size_t)wg * 256 + tid]       = fl[tid] + fl[128 + tid];
    partials[(size_t)wg * 256 + 128 + tid] = fl[256 + tid] + fl[384 + tid];
  }
}

// ---------------- reduce per-block partials -> mean / rsqrt ----------------
__global__ __launch_bounds__(256) void k_stats2(const float* __restrict__ partials, float* __restrict__ stats){
  int c = blockIdx.x;           // 0..255
  int mt = c >> 7, cl = c & 127;
  int t = threadIdx.x;
  float s = 0.f, q = 0.f;
  for (int idx = t; idx < 1568; idx += 256){
    const float* p = partials + (size_t)(2 * idx + mt) * 256;
    s += p[cl]; q += p[128 + cl];
  }
  __shared__ float r1[256], r2[256];
  r1[t] = s; r2[t] = q; __syncthreads();
  for (int off = 128; off > 0; off >>= 1){
    if (t < off){ r1[t] += r1[t + off]; r2[t] += r2[t + off]; }
    __syncthreads();
  }
  if (t == 0){
    float mean = r1[0] * (1.f / 200704.f);
    float var  = r2[0] * (1.f / 200704.f) - mean * mean;
    stats[c] = mean;
    stats[256 + c] = rsqrtf(var + 1e-5f);
  }
}

// ---------------- normalize: bf16 y -> fp32 out (int32 indexing) ----------------
__global__ __launch_bounds__(256) void k_norm(const unsigned short* __restrict__ ybf,
                                              const float* __restrict__ stats,
                                              const float* __restrict__ gamma, const float* __restrict__ beta,
                                              float* __restrict__ out){
  const int total = 6422528;   // 51380224 / 8
  for (int idx = blockIdx.x * 256 + threadIdx.x; idx < total; idx += gridDim.x * 256){
    int c = (idx / 6272) & 255;  // 6272 = 50176/8 ; 32-bit magic div
    float sc = stats[256 + c] * gamma[c];
    float sh = beta[c] - stats[c] * sc;
    short8 v = *(const short8*)(ybf + (size_t)idx * 8);
    float4 o0, o1;
    o0.x = bf2f((unsigned short)v[0]) * sc + sh;
    o0.y = bf2f((unsigned short)v[1]) * sc + sh;
    o0.z = bf2f((unsigned short)v[2]) * sc + sh;
    o0.w = bf2f((unsigned short)v[3]) * sc + sh;
    o1.x = bf2f((unsigned short)v[4]) * sc + sh;
    o1.y = bf2f((unsigned short)v[5]) * sc + sh;
    o1.z = bf2f((unsigned short)v[6]) * sc + sh;
    o1.w = bf2f((unsigned short)v[7]) * sc + sh;
    *(float4*)(out + (size_t)idx * 8)     = o0;
    *(float4*)(out + (size_t)idx * 8 + 4) = o1;
  }
}

extern "C" void kernel_launch(void* const* d_in, const int* in_sizes, int n_in,
                              void* d_out, int out_size, void* d_ws, size_t ws_size,
                              hipStream_t stream){
  const float* x     = (const float*)d_in[0];
  const float* Wq    = (const float*)d_in[1];
  const float* Wk    = (const float*)d_in[2];
  const float* Wv    = (const float*)d_in[3];
  const float* Wo    = (const float*)d_in[4];
  const float* gamma = (const float*)d_in[5];
  const float* beta  = (const float*)d_in[6];
  float* out = (float*)d_out;

  char* ws = (char*)d_ws;
  unsigned short* Wf     = (unsigned short*)ws;                               // 393216 B
  unsigned short* Wo_b   = (unsigned short*)(ws + 393216);                    // 131072 B
  float*          stats  = (float*)(ws + 524288);                             // 2048 B
  unsigned short* xw     = (unsigned short*)(ws + 1048576);                   // 134217728 B
  unsigned short* attnP  = (unsigned short*)(ws + 1048576 + 134217728);       // 102760448 B
  float*          partials = (float*)(ws + 1048576 + 134217728 + 102760448);  // 3211264 B
  unsigned short* ybf    = xw;   // alias: xw dead after k_fused (stream-ordered)

  k_convw<<<128, 256, 0, stream>>>(Wq, Wk, Wv, Wo, Wf, Wo_b);
  k_xw<<<2048, 256, 0, stream>>>(x, xw);
  k_fused<<<8192, 256, 0, stream>>>(xw, Wf, attnP);
  k_gemm_out<<<3136, 256, 0, stream>>>(Wo_b, attnP, x, ybf, partials);
  k_stats2<<<256, 256, 0, stream>>>(partials, stats);
  k_norm<<<4096, 256, 0, stream>>>(ybf, stats, gamma, beta, out);
}

// Round 18
// 428.343 us; speedup vs baseline: 1.1144x; 1.0105x over previous
//
#include <hip/hip_runtime.h>
#include <stdint.h>

typedef __attribute__((ext_vector_type(8))) short short8;
typedef __attribute__((ext_vector_type(4))) float f32x4;

#define MFMA16(a,b,c) __builtin_amdgcn_mfma_f32_16x16x32_bf16((a),(b),(c),0,0,0)

// async global->LDS DMA, 16B per lane; LDS dest = wave-uniform base + lane*16B
#define GLL16(g, l) __builtin_amdgcn_global_load_lds( \
    (const __attribute__((address_space(1))) void*)(g), \
    (__attribute__((address_space(3))) void*)(l), 16, 0, 0)

__device__ __forceinline__ unsigned short f2bf(float f){
  unsigned u = __builtin_bit_cast(unsigned, f);
  u += 0x7fffu + ((u >> 16) & 1u);
  return (unsigned short)(u >> 16);
}
__device__ __forceinline__ float bf2f(unsigned short s){
  unsigned u = ((unsigned)s) << 16;
  return __builtin_bit_cast(float, u);
}
__device__ __forceinline__ float fmax3(float a, float b, float c){
  return fmaxf(fmaxf(a, b), c);              // clang fuses to v_max3_f32
}
// pack 4 f32 -> 4 bf16 in a u64 (RNE, proven f2bf path)
__device__ __forceinline__ unsigned long long pack4(f32x4 v){
  return (unsigned long long)f2bf(v[0])
       | ((unsigned long long)f2bf(v[1]) << 16)
       | ((unsigned long long)f2bf(v[2]) << 32)
       | ((unsigned long long)f2bf(v[3]) << 48);
}

static constexpr int HW_ = 50176;   // 224*224

// offset of element (row r 0..127, k c64 0..63) inside one 8192-elem panel,
// XOR-swizzled so ds_read_b128 of a 16-lane column slice is conflict-free
__device__ __forceinline__ int panel_off(int r, int c64){
  return r * 64 + ((((c64 >> 3) ^ (r & 7))) << 3) + (c64 & 7);
}

// ---------------- weights fp32 -> bf16 ----------------
__global__ __launch_bounds__(256) void k_convw(const float* __restrict__ Wq, const float* __restrict__ Wk,
                        const float* __restrict__ Wv, const float* __restrict__ Wo,
                        unsigned short* __restrict__ Wf, unsigned short* __restrict__ Wob){
  int gid = blockIdx.x * 256 + threadIdx.x;   // grid 128 -> 32768
  if (gid < 24576){
    int lane = gid & 63;
    int r1 = gid >> 6;          // 0..383
    int t = r1 % 6;
    int r2 = r1 / 6;            // 0..63
    int kq = r2 & 7, hh = r2 >> 3;
    const float* W = (t < 2) ? Wq : (t < 4) ? Wk : Wv;
    int ch = hh * 32 + (t & 1) * 16 + (lane & 15);
    int k0 = kq * 32 + (lane >> 4) * 8;
    const float* src = W + ch * 256 + k0;
    float4 a = *(const float4*)src, b2 = *(const float4*)(src + 4);
    short8 v;
    v[0]=f2bf(a.x); v[1]=f2bf(a.y); v[2]=f2bf(a.z); v[3]=f2bf(a.w);
    v[4]=f2bf(b2.x); v[5]=f2bf(b2.y); v[6]=f2bf(b2.z); v[7]=f2bf(b2.w);
    *(short8*)(Wf + (size_t)gid * 8) = v;
  } else {
    int og = gid - 24576;       // 0..8191
    int o = og >> 5, ck = og & 31;
    const float* src = Wo + o * 256 + ck * 8;
    float4 a = *(const float4*)src, b2 = *(const float4*)(src + 4);
    short8 v;
    v[0]=f2bf(a.x); v[1]=f2bf(a.y); v[2]=f2bf(a.z); v[3]=f2bf(a.w);
    v[4]=f2bf(b2.x); v[5]=f2bf(b2.y); v[6]=f2bf(b2.z); v[7]=f2bf(b2.w);
    int kq = ck >> 3;
    int off = panel_off(o & 127, (ck & 7) * 8);
    *(short8*)(Wob + ((o >> 7) * 4 + kq) * 8192 + off) = v;
  }
}

// ---------------- x (B,C,H,W) f32 -> xw[win][half 2][px 49/64][128c swz] bf16 ----------------
__global__ __launch_bounds__(256) void k_xw(const float* __restrict__ x, unsigned short* __restrict__ xw){
  int bid = blockIdx.x;
  int cq = bid & 15, wh = (bid >> 4) & 31, b = bid >> 9;
  __shared__ __align__(16) unsigned short tile[25088];  // 49 KB
  int tid = threadIdx.x;
  for (int it = 0; it < 25; ++it){
    int idx = it * 256 + tid;
    if (idx < 6272){
      int c = idx & 15;
      int t2 = idx >> 4;                  // 0..391
      int r = t2 / 56;
      int w4 = t2 % 56;
      float4 v = *(const float4*)(x + ((size_t)(b * 256 + cq * 16 + c)) * HW_ + (wh * 7 + r) * 224 + w4 * 4);
      float vv[4] = {v.x, v.y, v.z, v.w};
      int w0 = w4 * 4;
      int ww = w0 / 7;
      int cl = w0 % 7;
#pragma unroll
      for (int i = 0; i < 4; ++i){
        int px = r * 7 + cl;
        tile[ww * 784 + px * 16 + (((c >> 3) ^ (px & 1)) << 3) + (c & 7)] = f2bf(vv[i]);
        if (++cl == 7){ cl = 0; ++ww; }
      }
    }
  }
  __syncthreads();
  size_t wb = ((size_t)(b * 1024 + wh * 32)) * 16384;
  for (int it = 0; it < 13; ++it){
    int id = it * 256 + tid;
    if (id < 3136){                       // 32 ww x 49 px x 2 chunk-slots
      int ww = id / 98;
      int rem = id - ww * 98;
      int px = rem >> 1, hb = rem & 1;
      short8 v = *(const short8*)(tile + ww * 784 + px * 16 + ((hb ^ (px & 1)) << 3));
      int cc = cq * 2 + hb;               // global 8-ch chunk 0..31
      int half = cc >> 4, c4 = cc & 15;
      int pos = (c4 & 8) | ((c4 ^ px) & 7);
      *(short8*)(xw + wb + (size_t)ww * 16384 + half * 8192 + px * 128 + pos * 8) = v;
    }
  }
}

// ---------------- fused: qkv GEMM + window attention ----------------
// block = (window, 4-head half), 4 waves = 4 heads, 48 KB LDS -> 3 blocks/CU
// x0 at [0,8192), x1 at [8192,16384) (overlapped DMA, counted vmcnt);
// q overwrites x1, vT overwrites x0 after a single post-phase-1 barrier.
__global__ __launch_bounds__(256, 3) void k_fused(const unsigned short* __restrict__ xw,
                                                  const unsigned short* __restrict__ Wf,
                                                  unsigned short* __restrict__ attnP){
  int bid = blockIdx.x;
  int wg = (bid & 7) * 1024 + (bid >> 3);   // 8192 = 8*1024; window pair on same XCD
  int hh = wg & 1; int win = wg >> 1;
  int b = win >> 10;
  int wh = (win >> 5) & 31, ww = win & 31;
  int tid = threadIdx.x;
  int lane = tid & 63;
  int hl = tid >> 6;                         // local head 0..3
  int hg = hh * 4 + hl;                      // global head

  __shared__ __align__(16) unsigned short lds[24576];   // 48 KB

  const unsigned short* xwin = xw + (size_t)win * 16384;

  // ---- phase 0: zero pad rows 49..63 of BOTH x buffers + overlapped DMA ----
  if (tid < 240){
    int rr = 49 + (tid >> 4), ck = tid & 15;
    short8 z = {};
    *(short8*)(lds + rr * 128 + ck * 8) = z;
    *(short8*)(lds + 8192 + rr * 128 + ck * 8) = z;
  }
#pragma unroll
  for (int it = 0; it < 4; ++it){
    int chunk = it * 256 + tid;              // x half0 -> [0,8192)
    if (chunk < 784) GLL16(xwin + chunk * 8, lds + chunk * 8);
  }
#pragma unroll
  for (int it = 0; it < 4; ++it){
    int chunk = it * 256 + tid;              // x half1 -> [8192,16384), stays in flight
    if (chunk < 784) GLL16(xwin + 8192 + chunk * 8, lds + 8192 + chunk * 8);
  }
  if (hl == 0) asm volatile("s_waitcnt vmcnt(4) lgkmcnt(0)" ::: "memory");  // wave0: 4 x1 ops remain
  else         asm volatile("s_waitcnt vmcnt(3) lgkmcnt(0)" ::: "memory");  // waves1-3: 3 remain
  __builtin_amdgcn_s_barrier();              // x0 (and zero-fill) visible to all waves

  // ---- phase 1: qkv GEMM; q,k transposed (D[ch][px]); v natural (D[px][ch]) ----
  f32x4 aqT[2][4] = {}, akT[2][4] = {}, avN[4][2] = {};
  for (int half = 0; half < 2; ++half){
    const unsigned short* xb = lds + half * 8192;
    for (int kq = 0; kq < 4; ++kq){
      short8 xf[4];
#pragma unroll
      for (int pt = 0; pt < 4; ++pt){
        int px = pt * 16 + (lane & 15);
        int c = kq * 4 + (lane >> 4);        // chunk 0..15
        int cs = (c & 8) | ((c ^ px) & 7);
        xf[pt] = *(const short8*)(xb + px * 128 + cs * 8);
      }
      short8 wfr[6];
      int kqg = half * 4 + kq;
#pragma unroll
      for (int t = 0; t < 6; ++t)
        wfr[t] = *(const short8*)(Wf + ((size_t)((hg * 8 + kqg) * 6 + t) * 64 + lane) * 8);
#pragma unroll
      for (int pt = 0; pt < 4; ++pt){
        aqT[0][pt] = MFMA16(wfr[0], xf[pt], aqT[0][pt]);   // D[ch][px]
        aqT[1][pt] = MFMA16(wfr[1], xf[pt], aqT[1][pt]);
        akT[0][pt] = MFMA16(wfr[2], xf[pt], akT[0][pt]);
        akT[1][pt] = MFMA16(wfr[3], xf[pt], akT[1][pt]);
        avN[pt][0] = MFMA16(xf[pt], wfr[4], avN[pt][0]);   // D[px][ch]
        avN[pt][1] = MFMA16(xf[pt], wfr[5], avN[pt][1]);
      }
    }
    if (half == 0){
      asm volatile("s_waitcnt vmcnt(0)" ::: "memory");  // own x1 DMAs landed
      __builtin_amdgcn_s_barrier();                     // all waves' x1 landed
    }
  }
  __syncthreads();                           // all x reads done -> x0/x1 become vT/q

  // write q,k -> [px][128ch swz], b64-packed (lane rows = 4 consecutive ch)
#pragma unroll
  for (int t = 0; t < 2; ++t)
#pragma unroll
    for (int pt = 0; pt < 4; ++pt){
      int px = pt * 16 + (lane & 15);
      int ck = hl * 4 + t * 2 + ((lane >> 4) >> 1);     // chl>>3, const over j
      int sub = ((lane >> 4) & 1) * 4;                  // chl&7 base
      int pos = px * 128 + (((ck & 8) | ((ck ^ px) & 7)) << 3) + sub;
      *(unsigned long long*)(lds + 8192 + pos)  = pack4(aqT[t][pt]);   // over x1
      *(unsigned long long*)(lds + 16384 + pos) = pack4(akT[t][pt]);
    }
  // write vT -> x0 region [128ch][64px swz], b64-packed (lane rows = 4 consecutive px)
#pragma unroll
  for (int ct = 0; ct < 2; ++ct)
#pragma unroll
    for (int pt = 0; pt < 4; ++pt){
      int chl = hl * 32 + ct * 16 + (lane & 15);
      int pxb = pt * 16 + ((lane >> 4) << 2);
      int addr = chl * 64 + (((pxb >> 3) ^ (chl & 7)) << 3) + (pxb & 7);
      *(unsigned long long*)(lds + addr) = pack4(avN[pt][ct]);
    }

  // ---- phase 2: S^T = K * Q^T (own head's q,k -- written by THIS wave, in-order LDS) ----
  short8 kf[4], qf[4];
#pragma unroll
  for (int i = 0; i < 4; ++i){
    int px = i * 16 + (lane & 15);
    int c = hl * 4 + (lane >> 4);            // own head's chunks
    int cs = (c & 8) | ((c ^ px) & 7);
    qf[i] = *(const short8*)(lds + 8192 + px * 128 + cs * 8);
    kf[i] = *(const short8*)(lds + 16384 + px * 128 + cs * 8);
  }
  f32x4 s[4][4] = {};
#pragma unroll
  for (int mi = 0; mi < 4; ++mi)
#pragma unroll
    for (int ni = 0; ni < 4; ++ni)
      s[mi][ni] = MFMA16(kf[mi], qf[ni], s[mi][ni]);
  __syncthreads();                           // all q/k reads + vT writes visible; q+k -> sP

  // ---- softmax over k' per q column; P (unnormalized) b64-packed to own sP ----
  const float cexp = 0.25504437f;            // log2(e)/sqrt(32)
  unsigned short* sP = lds + 8192 + hl * 4096;
  bool q0 = (lane < 16);
  float invs[4];
#pragma unroll
  for (int ni = 0; ni < 4; ++ni){
    float m0 = fmax3(s[0][ni][0], s[0][ni][1], s[0][ni][2]);
    float m1 = fmax3(s[0][ni][3], s[1][ni][0], s[1][ni][1]);
    float m2 = fmax3(s[1][ni][2], s[1][ni][3], s[2][ni][0]);
    float m3 = fmax3(s[2][ni][1], s[2][ni][2], s[2][ni][3]);
    float m = fmax3(m0, m1, m2);
    m = fmaxf(m, m3);
    m = fmaxf(m, q0 ? s[3][ni][0] : -3.0e38f);
    m = fmaxf(m, __shfl_xor(m, 16));
    m = fmaxf(m, __shfl_xor(m, 32));
    float sum = 0.f;
    float pv[4][4];
#pragma unroll
    for (int mi = 0; mi < 3; ++mi)
#pragma unroll
      for (int r = 0; r < 4; ++r){
        float e2 = exp2f((s[mi][ni][r] - m) * cexp);
        pv[mi][r] = e2; sum += e2;
      }
    {
      float e2 = q0 ? exp2f((s[3][ni][0] - m) * cexp) : 0.f;
      pv[3][0] = e2; sum += e2;
      pv[3][1] = 0.f; pv[3][2] = 0.f; pv[3][3] = 0.f;
    }
    sum += __shfl_xor(sum, 16);
    sum += __shfl_xor(sum, 32);
    invs[ni] = 1.0f / sum;                   // applied to O after PV (saves 16 mults/ni here)
    int q = ni * 16 + (lane & 15);
#pragma unroll
    for (int mi = 0; mi < 4; ++mi){
      int kpb2 = mi * 32 + ((lane >> 4) << 3);          // byte offset of 4-kp group
      int bo = (q * 128 + kpb2) ^ ((q & 7) << 4);
      unsigned long long pk =
          (unsigned long long)f2bf(pv[mi][0])
        | ((unsigned long long)f2bf(pv[mi][1]) << 16)
        | ((unsigned long long)f2bf(pv[mi][2]) << 32)
        | ((unsigned long long)f2bf(pv[mi][3]) << 48);
      *(unsigned long long*)((char*)sP + bo) = pk;
    }
  }

  // ---- phase 3: O^T = V^T * P^T (own sP + own vT rows); D[ch][q] ----
  f32x4 oT[2][4] = {};
#pragma unroll
  for (int kc = 0; kc < 2; ++kc){
    short8 pa[4], vb[2];
#pragma unroll
    for (int mtp = 0; mtp < 4; ++mtp){
      int row = mtp * 16 + (lane & 15);
      int bo = (row * 128 + kc * 64 + (lane >> 4) * 16) ^ ((row & 7) << 4);
      pa[mtp] = *(const short8*)((char*)sP + bo);
    }
#pragma unroll
    for (int ntp = 0; ntp < 2; ++ntp){
      int chl = hl * 32 + ntp * 16 + (lane & 15);
      int k0 = kc * 32 + (lane >> 4) * 8;
      vb[ntp] = *(const short8*)(lds + chl * 64 + (((k0 >> 3) ^ (chl & 7)) << 3));
    }
#pragma unroll
    for (int mtp = 0; mtp < 4; ++mtp)
#pragma unroll
      for (int ntp = 0; ntp < 2; ++ntp)
        oT[ntp][mtp] = MFMA16(vb[ntp], pa[mtp], oT[ntp][mtp]);
  }
  // O -> own sP area [64px(q)][32ch swz], b64-packed; fold 1/sum here
  // lane owns col q = mtp*16+(lane&15) == the q invs[mtp] was computed for
#pragma unroll
  for (int ntp = 0; ntp < 2; ++ntp)
#pragma unroll
    for (int mtp = 0; mtp < 4; ++mtp){
      f32x4 ov = oT[ntp][mtp] * invs[mtp];
      int px = mtp * 16 + (lane & 15);
      int chb = ntp * 16 + ((lane >> 4) << 2);
      int c2 = chb >> 3;
      int addr = px * 32 + (((c2 ^ px) & 3) << 3) + (chb & 7);
      *(unsigned long long*)(sP + addr) = pack4(ov);
    }
  __syncthreads();

  // ---- phase 4: cooperative 16B panel stores (this block's 4 heads) ----
  size_t pb0 = (size_t)b * 392 * 4;
#pragma unroll
  for (int it = 0; it < 4; ++it){
    int id = it * 256 + tid;                 // 0..1023 = 64px * 16 chunks
    int px = id >> 4, ck = id & 15;
    if (px < 49){
      int hl2 = ck >> 2, c2 = ck & 3;
      short8 v = *(const short8*)(lds + 8192 + hl2 * 4096 + px * 32 + (((c2 ^ px) & 3) << 3));
      int ch0 = (hh * 4 + hl2) * 32 + c2 * 8;
      int pg = (wh * 7 + px / 7) * 224 + ww * 7 + px % 7;
      int nt = pg >> 7, pr = pg & 127;
      size_t off = (pb0 + (size_t)nt * 4 + (ch0 >> 6)) * 8192 + panel_off(pr, ch0 & 63);
      *(short8*)(attnP + off) = v;
    }
  }
}

// ---------------- GEMM out + residual (bf16 y) + per-block BN partials ----------------
// counted-vmcnt 2-deep pipeline; epilogue restaged via LDS for full-sector ybf stores
__global__ __launch_bounds__(256) void k_gemm_out(const unsigned short* __restrict__ Wp,
                                                  const unsigned short* __restrict__ Bp,
                                                  const float* __restrict__ x,
                                                  unsigned short* __restrict__ ybf,
                                                  float* __restrict__ partials){
  int bid = blockIdx.x;
  int wg = (bid & 7) * 392 + (bid >> 3);     // 3136 = 8*392
  int mt = wg & 1; int rest = wg >> 1;       // mt fastest
  int nt = rest % 392; int b = rest / 392;

  __shared__ __align__(16) unsigned short lds[32768];  // dbuf (2 x 32KB); epilogue: [128 o][136] tile

  int tid = threadIdx.x;
  int lane = tid & 63;
  int wave = tid >> 6;
  int wm = wave >> 1, wn = wave & 1;

  const unsigned short* Apan = Wp + (size_t)mt * 4 * 8192;
  const unsigned short* Bpan = Bp + ((size_t)(b * 392 + nt)) * 4 * 8192;

  int aoff[2][4], boff[2][4];
#pragma unroll
  for (int kk = 0; kk < 2; ++kk)
#pragma unroll
    for (int i = 0; i < 4; ++i){
      int rowA = wm * 64 + i * 16 + (lane & 15);
      aoff[kk][i] = rowA * 64 + (((kk * 4 + (lane >> 4)) ^ (rowA & 7)) << 3);
      int rowB = wn * 64 + i * 16 + (lane & 15);
      boff[kk][i] = rowB * 64 + (((kk * 4 + (lane >> 4)) ^ (rowB & 7)) << 3);
    }
  int cb = wave * 2048;
  f32x4 acc[4][4] = {};

  // prologue: T0 -> buf0, T1 -> buf1 (16 loads in flight per wave)
#pragma unroll
  for (int j = 0; j < 4; ++j){
    int o2 = cb + j * 512;
    GLL16(Apan + o2 + lane * 8, lds + o2);
    GLL16(Bpan + o2 + lane * 8, lds + 8192 + o2);
  }
#pragma unroll
  for (int j = 0; j < 4; ++j){
    int o2 = cb + j * 512;
    GLL16(Apan + 8192 + o2 + lane * 8, lds + 16384 + o2);
    GLL16(Bpan + 8192 + o2 + lane * 8, lds + 24576 + o2);
  }

  int cur = 0;
  for (int kq = 0; kq < 4; ++kq){
    if (kq < 3) asm volatile("s_waitcnt vmcnt(8)" ::: "memory");  // tile kq landed; next stays in flight
    else        asm volatile("s_waitcnt vmcnt(0)" ::: "memory");
    __builtin_amdgcn_s_barrier();
    const unsigned short* Alds = lds + cur * 16384;
    const unsigned short* Blds = Alds + 8192;
#pragma unroll
    for (int kk = 0; kk < 2; ++kk){
      short8 af[4], bfv[4];
#pragma unroll
      for (int i = 0; i < 4; ++i) af[i]  = *(const short8*)(Alds + aoff[kk][i]);
#pragma unroll
      for (int j = 0; j < 4; ++j) bfv[j] = *(const short8*)(Blds + boff[kk][j]);
#pragma unroll
      for (int i = 0; i < 4; ++i)
#pragma unroll
        for (int j = 0; j < 4; ++j)
          acc[i][j] = MFMA16(af[i], bfv[j], acc[i][j]);
    }
    asm volatile("s_waitcnt lgkmcnt(0)" ::: "memory");   // this wave's LDS reads consumed
    __builtin_amdgcn_s_barrier();                        // all waves done reading buf[cur]
    if (kq < 2){
      const unsigned short* Ak = Apan + (kq + 2) * 8192;
      const unsigned short* Bk = Bpan + (kq + 2) * 8192;
      unsigned short* dst = lds + cur * 16384;
#pragma unroll
      for (int j = 0; j < 4; ++j){
        int o2 = cb + j * 512;
        GLL16(Ak + o2 + lane * 8, dst + o2);
        GLL16(Bk + o2 + lane * 8, dst + 8192 + o2);
      }
    }
    cur ^= 1;
  }
  // epilogue A: residual add -> LDS out-tile [o 128][pitch 136] u16, partials in regs
  unsigned short* lo = lds;                  // staging fully drained by final loop barrier
  float ps[4][4] = {}, pq[4][4] = {};
#pragma unroll
  for (int i = 0; i < 4; ++i)
#pragma unroll
    for (int j = 0; j < 4; ++j){
      int o_loc = wm * 64 + i * 16 + (lane >> 4) * 4;
      int p_loc = wn * 64 + j * 16 + (lane & 15);
      size_t base = ((size_t)(b * 256 + mt * 128 + o_loc)) * HW_ + nt * 128 + p_loc;
#pragma unroll
      for (int r2 = 0; r2 < 4; ++r2){
        float v = acc[i][j][r2] + x[base + (size_t)r2 * HW_];
        lo[(o_loc + r2) * 136 + p_loc] = f2bf(v);
        ps[i][r2] += v;
        pq[i][r2] += v * v;
      }
    }
  __syncthreads();
  // epilogue B: coalesced ybf stores (16 lanes x 16B = full 256B rows)
  {
    size_t orow0 = ((size_t)(b * 256 + mt * 128)) * HW_ + (size_t)nt * 128;
#pragma unroll
    for (int it2 = 0; it2 < 8; ++it2){
      int id = it2 * 256 + tid;              // 0..2047 = 128 o-rows x 16 chunks
      int o_loc = id >> 4, c16 = id & 15;
      short8 v = *(const short8*)(lo + o_loc * 136 + c16 * 8);
      *(short8*)(ybf + orow0 + (size_t)o_loc * HW_ + c16 * 8) = v;
    }
  }
  __syncthreads();                           // all LDS reads done before fl overwrite
  float* fl = (float*)lds;    // [wn 2][cl 128] sums, +256 sq
#pragma unroll
  for (int i = 0; i < 4; ++i)
#pragma unroll
    for (int r2 = 0; r2 < 4; ++r2){
      float a = ps[i][r2], q2 = pq[i][r2];
      a += __shfl_xor(a, 1);  q2 += __shfl_xor(q2, 1);
      a += __shfl_xor(a, 2);  q2 += __shfl_xor(q2, 2);
      a += __shfl_xor(a, 4);  q2 += __shfl_xor(q2, 4);
      a += __shfl_xor(a, 8);  q2 += __shfl_xor(q2, 8);
      if ((lane & 15) == 0){
        int cl = wm * 64 + i * 16 + (lane >> 4) * 4 + r2;
        fl[wn * 128 + cl] = a;
        fl[256 + wn * 128 + cl] = q2;
      }
    }
  __syncthreads();
  if (tid < 128){
    partials[(size_t)wg * 256 + tid]       = fl[tid] + fl[128 + tid];
    partials[(size_t)wg * 256 + 128 + tid] = fl[256 + tid] + fl[384 + tid];
  }
}

// ---------------- reduce per-block partials -> mean / rsqrt ----------------
__global__ __launch_bounds__(256) void k_stats2(const float* __restrict__ partials, float* __restrict__ stats){
  int c = blockIdx.x;           // 0..255
  int mt = c >> 7, cl = c & 127;
  int t = threadIdx.x;
  float s = 0.f, q = 0.f;
  for (int idx = t; idx < 1568; idx += 256){
    const float* p = partials + (size_t)(2 * idx + mt) * 256;
    s += p[cl]; q += p[128 + cl];
  }
  __shared__ float r1[256], r2[256];
  r1[t] = s; r2[t] = q; __syncthreads();
  for (int off = 128; off > 0; off >>= 1){
    if (t < off){ r1[t] += r1[t + off]; r2[t] += r2[t + off]; }
    __syncthreads();
  }
  if (t == 0){
    float mean = r1[0] * (1.f / 200704.f);
    float var  = r2[0] * (1.f / 200704.f) - mean * mean;
    stats[c] = mean;
    stats[256 + c] = rsqrtf(var + 1e-5f);
  }
}

// ---------------- normalize: bf16 y -> fp32 out (int32 indexing) ----------------
__global__ __launch_bounds__(256) void k_norm(const unsigned short* __restrict__ ybf,
                                              const float* __restrict__ stats,
                                              const float* __restrict__ gamma, const float* __restrict__ beta,
                                              float* __restrict__ out){
  const int total = 6422528;   // 51380224 / 8
  for (int idx = blockIdx.x * 256 + threadIdx.x; idx < total; idx += gridDim.x * 256){
    int c = (idx / 6272) & 255;  // 6272 = 50176/8 ; 32-bit magic div
    float sc = stats[256 + c] * gamma[c];
    float sh = beta[c] - stats[c] * sc;
    short8 v = *(const short8*)(ybf + (size_t)idx * 8);
    float4 o0, o1;
    o0.x = bf2f((unsigned short)v[0]) * sc + sh;
    o0.y = bf2f((unsigned short)v[1]) * sc + sh;
    o0.z = bf2f((unsigned short)v[2]) * sc + sh;
    o0.w = bf2f((unsigned short)v[3]) * sc + sh;
    o1.x = bf2f((unsigned short)v[4]) * sc + sh;
    o1.y = bf2f((unsigned short)v[5]) * sc + sh;
    o1.z = bf2f((unsigned short)v[6]) * sc + sh;
    o1.w = bf2f((unsigned short)v[7]) * sc + sh;
    *(float4*)(out + (size_t)idx * 8)     = o0;
    *(float4*)(out + (size_t)idx * 8 + 4) = o1;
  }
}

extern "C" void kernel_launch(void* const* d_in, const int* in_sizes, int n_in,
                              void* d_out, int out_size, void* d_ws, size_t ws_size,
                              hipStream_t stream){
  const float* x     = (const float*)d_in[0];
  const float* Wq    = (const float*)d_in[1];
  const float* Wk    = (const float*)d_in[2];
  const float* Wv    = (const float*)d_in[3];
  const float* Wo    = (const float*)d_in[4];
  const float* gamma = (const float*)d_in[5];
  const float* beta  = (const float*)d_in[6];
  float* out = (float*)d_out;

  char* ws = (char*)d_ws;
  unsigned short* Wf     = (unsigned short*)ws;                               // 393216 B
  unsigned short* Wo_b   = (unsigned short*)(ws + 393216);                    // 131072 B
  float*          stats  = (float*)(ws + 524288);                             // 2048 B
  unsigned short* xw     = (unsigned short*)(ws + 1048576);                   // 134217728 B
  unsigned short* attnP  = (unsigned short*)(ws + 1048576 + 134217728);       // 102760448 B
  float*          partials = (float*)(ws + 1048576 + 134217728 + 102760448);  // 3211264 B
  unsigned short* ybf    = xw;   // alias: xw dead after k_fused (stream-ordered)

  k_convw<<<128, 256, 0, stream>>>(Wq, Wk, Wv, Wo, Wf, Wo_b);
  k_xw<<<2048, 256, 0, stream>>>(x, xw);
  k_fused<<<8192, 256, 0, stream>>>(xw, Wf, attnP);
  k_gemm_out<<<3136, 256, 0, stream>>>(Wo_b, attnP, x, ybf, partials);
  k_stats2<<<256, 256, 0, stream>>>(partials, stats);
  k_norm<<<4096, 256, 0, stream>>>(ybf, stats, gamma, beta, out);
}